// Round 7
// baseline (1029.851 us; speedup 1.0000x reference)
//
#include <hip/hip_runtime.h>
#include <cstdint>
#include <cstddef>

#define N_NODES 100000
#define N_EDGES 500000
#define N_RELS  200
#define N_BASE  50
#define INIT_D  100
#define FEAT_D  128
#define N_CLS   50
#define BN_EPS  1e-5f

#define SCAN_BLK 1024
#define NB_SCAN  ((N_NODES + SCAN_BLK - 1) / SCAN_BLK)   // 98

typedef unsigned int uint;
typedef unsigned short ushort;
typedef float f4v __attribute__((ext_vector_type(4)));

// bf16 helpers (RNE pack, cheap unpack)
__device__ inline uint packbf2(float a, float b) {
  uint ua = __float_as_uint(a); ua = (ua + 0x7fffu + ((ua >> 16) & 1u)) >> 16;
  uint ub = __float_as_uint(b); ub = (ub + 0x7fffu + ((ub >> 16) & 1u)) >> 16;
  return ua | (ub << 16);
}
__device__ inline float bf_lo(uint u) { return __uint_as_float(u << 16); }
__device__ inline float bf_hi(uint u) { return __uint_as_float(u & 0xffff0000u); }

// ---------- fused: blocks 0..199 -> REL rows; blocks 200..299 -> WC rows ----------
__global__ __launch_bounds__(128)
void relwc_kernel(const float* __restrict__ rel_wt, const float* __restrict__ emb_e,
                  const float* __restrict__ W_e, float* __restrict__ REL,
                  const float* __restrict__ W_h, const float* __restrict__ aggre_W,
                  float* __restrict__ WC) {
  __shared__ float T[FEAT_D];
  int t = threadIdx.x;
  if (blockIdx.x < N_RELS) {
    int r = blockIdx.x;
    if (t < INIT_D) {
      float a = 0.f;
      for (int b = 0; b < N_BASE; ++b)
        a += rel_wt[r * N_BASE + b] * emb_e[b * INIT_D + t];
      T[t] = a;
    }
    __syncthreads();
    float a = 0.f;
    for (int k = 0; k < INIT_D; ++k)
      a += T[k] * W_e[k * FEAT_D + t];
    REL[r * FEAT_D + t] = a;
  } else {
    int i = blockIdx.x - N_RELS;
    T[t] = W_h[i * FEAT_D + t];
    __syncthreads();
    float a = 0.f;
    for (int f = 0; f < FEAT_D; ++f)
      a += T[f] * aggre_W[f * FEAT_D + t];
    WC[i * FEAT_D + t] = a;
  }
}

// ---------- H0 = relu(emb_h @ WC + b) -> bf16 ; also zeroes DEG and ACC ----------
__global__ __launch_bounds__(256)
void h0_kernel(const float* __restrict__ emb_h, const float* __restrict__ WC,
               const float* __restrict__ bias, ushort* __restrict__ H,
               int* __restrict__ deg, float* __restrict__ acc, int nNodes) {
  __shared__ float WT[FEAT_D * INIT_D];
  __shared__ float bs[FEAT_D];
  int t = threadIdx.x;
  {
    int g = blockIdx.x * 256 + t;
    if (g < N_NODES) deg[g] = 0;
    if (g < 2 * FEAT_D) acc[g] = 0.f;
  }
  for (int i = t; i < FEAT_D * INIT_D; i += 256) {
    int k = i >> 7, j = i & 127;
    WT[j * INIT_D + k] = WC[i];
  }
  if (t < FEAT_D) bs[t] = bias[t];
  __syncthreads();
  for (int n = blockIdx.x * 256 + t; n < nNodes; n += gridDim.x * 256) {
    float x[INIT_D];
    const float4* xp = (const float4*)(emb_h + (size_t)n * INIT_D);
#pragma unroll
    for (int q = 0; q < 25; ++q) {
      float4 v = xp[q];
      x[4 * q + 0] = v.x; x[4 * q + 1] = v.y; x[4 * q + 2] = v.z; x[4 * q + 3] = v.w;
    }
    uint2* orow = (uint2*)(H + (size_t)n * FEAT_D);
    for (int j4 = 0; j4 < 32; ++j4) {
      float4 a;
      a.x = bs[4 * j4 + 0]; a.y = bs[4 * j4 + 1];
      a.z = bs[4 * j4 + 2]; a.w = bs[4 * j4 + 3];
      const float4* w0 = (const float4*)&WT[(4 * j4 + 0) * INIT_D];
      const float4* w1 = (const float4*)&WT[(4 * j4 + 1) * INIT_D];
      const float4* w2 = (const float4*)&WT[(4 * j4 + 2) * INIT_D];
      const float4* w3 = (const float4*)&WT[(4 * j4 + 3) * INIT_D];
#pragma unroll
      for (int q = 0; q < 25; ++q) {
        float4 v0 = w0[q], v1 = w1[q], v2 = w2[q], v3 = w3[q];
        a.x = fmaf(x[4*q+0], v0.x, a.x); a.x = fmaf(x[4*q+1], v0.y, a.x);
        a.x = fmaf(x[4*q+2], v0.z, a.x); a.x = fmaf(x[4*q+3], v0.w, a.x);
        a.y = fmaf(x[4*q+0], v1.x, a.y); a.y = fmaf(x[4*q+1], v1.y, a.y);
        a.y = fmaf(x[4*q+2], v1.z, a.y); a.y = fmaf(x[4*q+3], v1.w, a.y);
        a.z = fmaf(x[4*q+0], v2.x, a.z); a.z = fmaf(x[4*q+1], v2.y, a.z);
        a.z = fmaf(x[4*q+2], v2.z, a.z); a.z = fmaf(x[4*q+3], v2.w, a.z);
        a.w = fmaf(x[4*q+0], v3.x, a.w); a.w = fmaf(x[4*q+1], v3.y, a.w);
        a.w = fmaf(x[4*q+2], v3.z, a.w); a.w = fmaf(x[4*q+3], v3.w, a.w);
      }
      a.x = fmaxf(a.x, 0.f); a.y = fmaxf(a.y, 0.f);
      a.z = fmaxf(a.z, 0.f); a.w = fmaxf(a.w, 0.f);
      uint2 pk; pk.x = packbf2(a.x, a.y); pk.y = packbf2(a.z, a.w);
      orow[j4] = pk;
    }
  }
}

// ---------- CSR build: histogram of dst ----------
__global__ __launch_bounds__(256)
void hist_kernel(const int* __restrict__ dst, int* __restrict__ deg, int nEdges) {
  for (int e = blockIdx.x * 256 + threadIdx.x; e < nEdges; e += gridDim.x * 256)
    atomicAdd(&deg[dst[e]], 1);
}

// ---------- CSR build: per-block sums of deg (coalesced int4) ----------
__global__ __launch_bounds__(256)
void scanA_kernel(const int* __restrict__ deg, int* __restrict__ bsum, int n) {
  __shared__ int red[256];
  int t = threadIdx.x;
  int base = blockIdx.x * SCAN_BLK + t * 4;
  int s = 0;
#pragma unroll
  for (int q = 0; q < 4; ++q) {
    int i = base + q;
    s += (i < n) ? deg[i] : 0;
  }
  red[t] = s;
  __syncthreads();
  for (int off = 128; off > 0; off >>= 1) {
    if (t < off) red[t] += red[t + off];
    __syncthreads();
  }
  if (t == 0) bsum[blockIdx.x] = red[0];
}

// ---------- CSR build: wave-parallel scan of the 98 block sums ----------
__global__ __launch_bounds__(128)
void scanBw_kernel(int* __restrict__ bsum, int nb, int* __restrict__ off) {
  __shared__ int s[128];
  int t = threadIdx.x;
  int v = (t < nb) ? bsum[t] : 0;
  s[t] = v;
  __syncthreads();
  for (int o = 1; o < 128; o <<= 1) {
    int u = (t >= o) ? s[t - o] : 0;
    __syncthreads();
    s[t] += u;
    __syncthreads();
  }
  if (t < nb) bsum[t] = s[t] - v;        // exclusive
  if (t == nb - 1) off[N_NODES] = s[t];  // total
}

// ---------- CSR build: final offsets (exclusive scan) + cursor copy ----------
__global__ __launch_bounds__(256)
void scanC_kernel(const int* __restrict__ deg, const int* __restrict__ bsum,
                  int* __restrict__ off, int* __restrict__ cur, int n) {
  __shared__ int lds[256];
  int t = threadIdx.x;
  int base = blockIdx.x * SCAN_BLK + t * 4;
  int d[4];
  int s = 0;
#pragma unroll
  for (int q = 0; q < 4; ++q) {
    int i = base + q;
    d[q] = (i < n) ? deg[i] : 0;
    s += d[q];
  }
  lds[t] = s;
  __syncthreads();
  for (int o = 1; o < 256; o <<= 1) {
    int v = (t >= o) ? lds[t - o] : 0;
    __syncthreads();
    lds[t] += v;
    __syncthreads();
  }
  int excl = lds[t] - s + bsum[blockIdx.x];
#pragma unroll
  for (int q = 0; q < 4; ++q) {
    int i = base + q;
    if (i < n) {
      off[i] = excl;
      cur[i] = excl;
    }
    excl += d[q];
  }
}

// ---------- CSR build: fill packed edge array ----------
__global__ __launch_bounds__(256)
void fill_kernel(const int* __restrict__ src, const int* __restrict__ dst,
                 const int* __restrict__ et, int* __restrict__ cur,
                 int* __restrict__ epk, int nEdges) {
  for (int e = blockIdx.x * 256 + threadIdx.x; e < nEdges; e += gridDim.x * 256) {
    int d = dst[e];
    int pos = atomicAdd(&cur[d], 1);
    epk[pos] = src[e] | (et[e] << 17);
  }
}

// ---------- gather-mean over bf16 H rows; nt stores of MEAN ----------
__global__ __launch_bounds__(256)
void gather_mean_kernel(const int* __restrict__ off, const int* __restrict__ epk,
                        const ushort* __restrict__ H, const float* __restrict__ REL,
                        float* __restrict__ MEAN, int doBN, float* __restrict__ acc,
                        int nNodes) {
  const uint2* H2 = (const uint2*)H;
  const float4* R4 = (const float4*)REL;
  int t = threadIdx.x;
  int j = t & 31;
  int slot = t >> 5;
  float4 s1 = {0.f, 0.f, 0.f, 0.f}, s2 = {0.f, 0.f, 0.f, 0.f};
  for (int n = blockIdx.x * 8 + slot; n < nNodes; n += gridDim.x * 8) {
    int beg = off[n], end = off[n + 1];
    float4 a = {0.f, 0.f, 0.f, 0.f};
    int p = beg;
#pragma unroll 1
    for (; p + 4 <= end; p += 4) {
      int u0 = epk[p + 0];
      int u1 = epk[p + 1];
      int u2 = epk[p + 2];
      int u3 = epk[p + 3];
      uint2 h0 = H2[(size_t)(u0 & 0x1FFFF) * 32 + j];
      uint2 h1 = H2[(size_t)(u1 & 0x1FFFF) * 32 + j];
      uint2 h2 = H2[(size_t)(u2 & 0x1FFFF) * 32 + j];
      uint2 h3 = H2[(size_t)(u3 & 0x1FFFF) * 32 + j];
      float4 r0 = R4[(u0 >> 17) * 32 + j];
      float4 r1 = R4[(u1 >> 17) * 32 + j];
      float4 r2 = R4[(u2 >> 17) * 32 + j];
      float4 r3 = R4[(u3 >> 17) * 32 + j];
      a.x += (bf_lo(h0.x) + r0.x) + (bf_lo(h1.x) + r1.x) +
             (bf_lo(h2.x) + r2.x) + (bf_lo(h3.x) + r3.x);
      a.y += (bf_hi(h0.x) + r0.y) + (bf_hi(h1.x) + r1.y) +
             (bf_hi(h2.x) + r2.y) + (bf_hi(h3.x) + r3.y);
      a.z += (bf_lo(h0.y) + r0.z) + (bf_lo(h1.y) + r1.z) +
             (bf_lo(h2.y) + r2.z) + (bf_lo(h3.y) + r3.z);
      a.w += (bf_hi(h0.y) + r0.w) + (bf_hi(h1.y) + r1.w) +
             (bf_hi(h2.y) + r2.w) + (bf_hi(h3.y) + r3.w);
    }
#pragma unroll 1
    for (; p < end; ++p) {
      int u = epk[p];
      uint2 hv = H2[(size_t)(u & 0x1FFFF) * 32 + j];
      float4 rv = R4[(u >> 17) * 32 + j];
      a.x += bf_lo(hv.x) + rv.x; a.y += bf_hi(hv.x) + rv.y;
      a.z += bf_lo(hv.y) + rv.z; a.w += bf_hi(hv.y) + rv.w;
    }
    float rd = (end > beg) ? 1.f / (float)(end - beg) : 0.f;
    a.x *= rd; a.y *= rd; a.z *= rd; a.w *= rd;
    f4v m; m[0] = a.x; m[1] = a.y; m[2] = a.z; m[3] = a.w;
    __builtin_nontemporal_store(m, (f4v*)(MEAN + (size_t)n * FEAT_D) + j);
    if (doBN) {
      s1.x += a.x; s1.y += a.y; s1.z += a.z; s1.w += a.w;
      s2.x += a.x * a.x; s2.y += a.y * a.y;
      s2.z += a.z * a.z; s2.w += a.w * a.w;
    }
  }
  if (doBN) {
    __shared__ float4 r1[8][32], r2[8][32];
    r1[slot][j] = s1;
    r2[slot][j] = s2;
    __syncthreads();
    if (slot == 0) {
      float4 a1 = r1[0][j], a2 = r2[0][j];
#pragma unroll
      for (int k = 1; k < 8; ++k) {
        float4 b1 = r1[k][j], b2 = r2[k][j];
        a1.x += b1.x; a1.y += b1.y; a1.z += b1.z; a1.w += b1.w;
        a2.x += b2.x; a2.y += b2.y; a2.z += b2.z; a2.w += b2.w;
      }
      atomicAdd(&acc[4 * j + 0], a1.x);
      atomicAdd(&acc[4 * j + 1], a1.y);
      atomicAdd(&acc[4 * j + 2], a1.z);
      atomicAdd(&acc[4 * j + 3], a1.w);
      atomicAdd(&acc[FEAT_D + 4 * j + 0], a2.x);
      atomicAdd(&acc[FEAT_D + 4 * j + 1], a2.y);
      atomicAdd(&acc[FEAT_D + 4 * j + 2], a2.z);
      atomicAdd(&acc[FEAT_D + 4 * j + 3], a2.w);
    }
  }
}

// ---------- H1 = relu(MEAN @ aggre_W + b) -> bf16 ; nt MEAN loads ; zeroes DEG ----------
__global__ __launch_bounds__(256)
void h1_kernel(const float* __restrict__ mean, const float* __restrict__ W,
               const float* __restrict__ bias, ushort* __restrict__ H,
               int* __restrict__ deg, int nNodes) {
  __shared__ float WT[FEAT_D * FEAT_D];
  __shared__ float bs[FEAT_D];
  int t = threadIdx.x;
  {
    int g = blockIdx.x * 256 + t;
    if (g < N_NODES) deg[g] = 0;
  }
  for (int i = t; i < FEAT_D * FEAT_D; i += 256) {
    int k = i >> 7, j = i & 127;
    WT[j * FEAT_D + k] = W[i];
  }
  if (t < FEAT_D) bs[t] = bias[t];
  __syncthreads();
  for (int n = blockIdx.x * 256 + t; n < nNodes; n += gridDim.x * 256) {
    float x[FEAT_D];
    const f4v* xp = (const f4v*)(mean + (size_t)n * FEAT_D);
#pragma unroll
    for (int q = 0; q < 32; ++q) {
      f4v v = __builtin_nontemporal_load(xp + q);
      x[4 * q + 0] = v[0]; x[4 * q + 1] = v[1];
      x[4 * q + 2] = v[2]; x[4 * q + 3] = v[3];
    }
    uint2* orow = (uint2*)(H + (size_t)n * FEAT_D);
    for (int j4 = 0; j4 < 32; ++j4) {
      float4 a;
      a.x = bs[4 * j4 + 0]; a.y = bs[4 * j4 + 1];
      a.z = bs[4 * j4 + 2]; a.w = bs[4 * j4 + 3];
      const float4* w0 = (const float4*)&WT[(4 * j4 + 0) * FEAT_D];
      const float4* w1 = (const float4*)&WT[(4 * j4 + 1) * FEAT_D];
      const float4* w2 = (const float4*)&WT[(4 * j4 + 2) * FEAT_D];
      const float4* w3 = (const float4*)&WT[(4 * j4 + 3) * FEAT_D];
#pragma unroll
      for (int q = 0; q < 32; ++q) {
        float4 v0 = w0[q], v1 = w1[q], v2 = w2[q], v3 = w3[q];
        a.x = fmaf(x[4*q+0], v0.x, a.x); a.x = fmaf(x[4*q+1], v0.y, a.x);
        a.x = fmaf(x[4*q+2], v0.z, a.x); a.x = fmaf(x[4*q+3], v0.w, a.x);
        a.y = fmaf(x[4*q+0], v1.x, a.y); a.y = fmaf(x[4*q+1], v1.y, a.y);
        a.y = fmaf(x[4*q+2], v1.z, a.y); a.y = fmaf(x[4*q+3], v1.w, a.y);
        a.z = fmaf(x[4*q+0], v2.x, a.z); a.z = fmaf(x[4*q+1], v2.y, a.z);
        a.z = fmaf(x[4*q+2], v2.z, a.z); a.z = fmaf(x[4*q+3], v2.w, a.z);
        a.w = fmaf(x[4*q+0], v3.x, a.w); a.w = fmaf(x[4*q+1], v3.y, a.w);
        a.w = fmaf(x[4*q+2], v3.z, a.w); a.w = fmaf(x[4*q+3], v3.w, a.w);
      }
      a.x = fmaxf(a.x, 0.f); a.y = fmaxf(a.y, 0.f);
      a.z = fmaxf(a.z, 0.f); a.w = fmaxf(a.w, 0.f);
      uint2 pk; pk.x = packbf2(a.x, a.y); pk.y = packbf2(a.z, a.w);
      orow[j4] = pk;
    }
  }
}

// ---------- final: BN -> relu -> MLP ; nt MEAN loads, nt out stores ----------
__global__ __launch_bounds__(256)
void final_kernel(const float* __restrict__ mean, const float* __restrict__ acc,
                  const float* __restrict__ gamma, const float* __restrict__ beta,
                  const float* __restrict__ fc0w, const float* __restrict__ fc0b,
                  const float* __restrict__ fc1w, const float* __restrict__ fc1b,
                  const float* __restrict__ fc2w, const float* __restrict__ fc2b,
                  float* __restrict__ out, int nNodes) {
  __shared__ float W0T[64 * FEAT_D];
  __shared__ float W1L[64 * 32];
  __shared__ float W2T[N_CLS * 32];
  __shared__ float sc[FEAT_D], sh[FEAT_D];
  __shared__ float b0[64], b1[32], b2[N_CLS];
  int t = threadIdx.x;
  for (int i = t; i < 64 * FEAT_D; i += 256) {
    int k = i >> 6, j = i & 63;
    W0T[j * FEAT_D + k] = fc0w[i];
  }
  for (int i = t; i < 64 * 32; i += 256) W1L[i] = fc1w[i];
  for (int i = t; i < 32 * N_CLS; i += 256) {
    int jj = i / N_CLS, c = i % N_CLS;
    W2T[c * 32 + jj] = fc2w[i];
  }
  if (t < FEAT_D) {
    float m = acc[t] * (1.f / (float)N_NODES);
    float v = acc[FEAT_D + t] * (1.f / (float)N_NODES) - m * m;
    float r = rsqrtf(v + BN_EPS);
    float g = gamma[t];
    sc[t] = r * g;
    sh[t] = beta[t] - m * r * g;
  }
  if (t < 64) b0[t] = fc0b[t];
  if (t < 32) b1[t] = fc1b[t];
  if (t < N_CLS) b2[t] = fc2b[t];
  __syncthreads();
  for (int n = blockIdx.x * 256 + t; n < nNodes; n += gridDim.x * 256) {
    float x[FEAT_D];
    const f4v* xp = (const f4v*)(mean + (size_t)n * FEAT_D);
#pragma unroll
    for (int q = 0; q < 32; ++q) {
      f4v v = __builtin_nontemporal_load(xp + q);
      x[4*q+0] = fmaxf(fmaf(v[0], sc[4*q+0], sh[4*q+0]), 0.f);
      x[4*q+1] = fmaxf(fmaf(v[1], sc[4*q+1], sh[4*q+1]), 0.f);
      x[4*q+2] = fmaxf(fmaf(v[2], sc[4*q+2], sh[4*q+2]), 0.f);
      x[4*q+3] = fmaxf(fmaf(v[3], sc[4*q+3], sh[4*q+3]), 0.f);
    }
    float acc2[32];
#pragma unroll
    for (int jj = 0; jj < 32; ++jj) acc2[jj] = b1[jj];
    for (int j = 0; j < 64; ++j) {
      float a = b0[j];
      const float4* w = (const float4*)&W0T[j * FEAT_D];
#pragma unroll
      for (int q = 0; q < 32; ++q) {
        float4 v = w[q];
        a = fmaf(x[4*q+0], v.x, a); a = fmaf(x[4*q+1], v.y, a);
        a = fmaf(x[4*q+2], v.z, a); a = fmaf(x[4*q+3], v.w, a);
      }
      float h = fmaxf(a, 0.f);
      const float4* w1 = (const float4*)&W1L[j * 32];
#pragma unroll
      for (int q = 0; q < 8; ++q) {
        float4 v = w1[q];
        acc2[4*q+0] = fmaf(h, v.x, acc2[4*q+0]);
        acc2[4*q+1] = fmaf(h, v.y, acc2[4*q+1]);
        acc2[4*q+2] = fmaf(h, v.z, acc2[4*q+2]);
        acc2[4*q+3] = fmaf(h, v.w, acc2[4*q+3]);
      }
    }
    float h2[32];
#pragma unroll
    for (int jj = 0; jj < 32; ++jj) h2[jj] = fmaxf(acc2[jj], 0.f);
    float* orow = out + (size_t)n * N_CLS;
    for (int cc = 0; cc < N_CLS; ++cc) {
      float a = b2[cc];
      const float4* w = (const float4*)&W2T[cc * 32];
#pragma unroll
      for (int q = 0; q < 8; ++q) {
        float4 v = w[q];
        a = fmaf(h2[4*q+0], v.x, a); a = fmaf(h2[4*q+1], v.y, a);
        a = fmaf(h2[4*q+2], v.z, a); a = fmaf(h2[4*q+3], v.w, a);
      }
      __builtin_nontemporal_store(a, &orow[cc]);
    }
  }
}

extern "C" void kernel_launch(void* const* d_in, const int* in_sizes, int n_in,
                              void* d_out, int out_size, void* d_ws, size_t ws_size,
                              hipStream_t stream) {
  const int* edge_src = (const int*)d_in[0];
  const int* edge_dst = (const int*)d_in[1];
  const int* edge_type = (const int*)d_in[2];
  const float* emb_h = (const float*)d_in[3];
  const float* emb_e = (const float*)d_in[4];
  const float* rel_wt = (const float*)d_in[5];
  const float* W_h_init = (const float*)d_in[6];
  const float* W_e_init = (const float*)d_in[7];
  const float* aggre_W = (const float*)d_in[8];
  const float* aggre_b = (const float*)d_in[9];
  const float* bn_gamma = (const float*)d_in[10];
  const float* bn_beta = (const float*)d_in[11];
  const float* fc0_w = (const float*)d_in[12];
  const float* fc0_b = (const float*)d_in[13];
  const float* fc1_w = (const float*)d_in[14];
  const float* fc1_b = (const float*)d_in[15];
  const float* fc2_w = (const float*)d_in[16];
  const float* fc2_b = (const float*)d_in[17];
  float* out = (float*)d_out;

  // ---- workspace layout (bytes): ~77 MB ----
  char* ws = (char*)d_ws;
  float*  REL  = (float*)(ws);                    // 102,400
  float*  WC   = (float*)(ws + 102400);           // 51,200
  ushort* H    = (ushort*)(ws + 153600);          // 25,600,000
  float*  MEAN = (float*)(ws + 25753600);         // 51,200,000
  float*  ACC  = (float*)(ws + 76953600);         // 1,024

  // ---- CSR scratch lives in d_out (20 MB); final_kernel overwrites it last ----
  char* ob = (char*)d_out;
  int* EPK  = (int*)(ob);                        // 2,000,000
  int* DEG  = (int*)(ob + 2000000);              // 400,000
  int* OFF  = (int*)(ob + 2400000);              // 400,004
  int* CUR  = (int*)(ob + 2800004);              // 400,004
  int* BSUM = (int*)(ob + 3200008);              // 392

  const int NODE_BLOCKS = (N_NODES + 255) / 256;  // 391
  const int GATHER_BLOCKS = 4096;

  relwc_kernel<<<N_RELS + INIT_D, 128, 0, stream>>>(rel_wt, emb_e, W_e_init, REL,
                                                    W_h_init, aggre_W, WC);
  h0_kernel<<<NODE_BLOCKS, 256, 0, stream>>>(emb_h, WC, aggre_b, H, DEG, ACC,
                                             N_NODES);

  // ---- layer 0: build CSR (DEG zeroed by h0) and gather ----
  hist_kernel<<<1024, 256, 0, stream>>>(edge_dst, DEG, N_EDGES);
  scanA_kernel<<<NB_SCAN, 256, 0, stream>>>(DEG, BSUM, N_NODES);
  scanBw_kernel<<<1, 128, 0, stream>>>(BSUM, NB_SCAN, OFF);
  scanC_kernel<<<NB_SCAN, 256, 0, stream>>>(DEG, BSUM, OFF, CUR, N_NODES);
  fill_kernel<<<1024, 256, 0, stream>>>(edge_src, edge_dst, edge_type, CUR, EPK,
                                        N_EDGES);
  gather_mean_kernel<<<GATHER_BLOCKS, 256, 0, stream>>>(OFF, EPK, H, REL, MEAN, 0,
                                                        ACC, N_NODES);

  h1_kernel<<<NODE_BLOCKS, 256, 0, stream>>>(MEAN, aggre_W, aggre_b, H, DEG,
                                             N_NODES);

  // ---- layer 1: build CSR (DEG zeroed by h1) and gather (+BN stats) ----
  hist_kernel<<<1024, 256, 0, stream>>>(edge_dst + N_EDGES, DEG, N_EDGES);
  scanA_kernel<<<NB_SCAN, 256, 0, stream>>>(DEG, BSUM, N_NODES);
  scanBw_kernel<<<1, 128, 0, stream>>>(BSUM, NB_SCAN, OFF);
  scanC_kernel<<<NB_SCAN, 256, 0, stream>>>(DEG, BSUM, OFF, CUR, N_NODES);
  fill_kernel<<<1024, 256, 0, stream>>>(edge_src + N_EDGES, edge_dst + N_EDGES,
                                        edge_type + N_EDGES, CUR, EPK, N_EDGES);
  gather_mean_kernel<<<GATHER_BLOCKS, 256, 0, stream>>>(OFF, EPK, H, REL, MEAN, 1,
                                                        ACC, N_NODES);

  final_kernel<<<NODE_BLOCKS, 256, 0, stream>>>(MEAN, ACC, bn_gamma, bn_beta,
                                                fc0_w, fc0_b, fc1_w, fc1_b,
                                                fc2_w, fc2_b, out, N_NODES);
}

// Round 8
// 828.481 us; speedup vs baseline: 1.2431x; 1.2431x over previous
//
#include <hip/hip_runtime.h>
#include <cstdint>
#include <cstddef>

#define N_NODES 100000
#define N_EDGES 500000
#define N_RELS  200
#define N_BASE  50
#define INIT_D  100
#define FEAT_D  128
#define N_CLS   50
#define BN_EPS  1e-5f

#define SCAN_BLK 1024
#define NB_SCAN  ((N_NODES + SCAN_BLK - 1) / SCAN_BLK)   // 98

typedef unsigned int uint;
typedef unsigned short ushort;
typedef float f4v __attribute__((ext_vector_type(4)));

// bf16 helpers (RNE pack, cheap unpack)
__device__ inline uint packbf2(float a, float b) {
  uint ua = __float_as_uint(a); ua = (ua + 0x7fffu + ((ua >> 16) & 1u)) >> 16;
  uint ub = __float_as_uint(b); ub = (ub + 0x7fffu + ((ub >> 16) & 1u)) >> 16;
  return ua | (ub << 16);
}
__device__ inline float bf_lo(uint u) { return __uint_as_float(u << 16); }
__device__ inline float bf_hi(uint u) { return __uint_as_float(u & 0xffff0000u); }

// ---------- fused: blocks 0..199 -> RELP rows (packed bf16); 200..299 -> WC ----------
__global__ __launch_bounds__(128)
void relwc_kernel(const float* __restrict__ rel_wt, const float* __restrict__ emb_e,
                  const float* __restrict__ W_e, uint* __restrict__ RELP,
                  const float* __restrict__ W_h, const float* __restrict__ aggre_W,
                  float* __restrict__ WC) {
  __shared__ float T[FEAT_D];
  int t = threadIdx.x;
  if (blockIdx.x < N_RELS) {
    int r = blockIdx.x;
    if (t < INIT_D) {
      float a = 0.f;
      for (int b = 0; b < N_BASE; ++b)
        a += rel_wt[r * N_BASE + b] * emb_e[b * INIT_D + t];
      T[t] = a;
    }
    __syncthreads();
    float a = 0.f;
    for (int k = 0; k < INIT_D; ++k)
      a += T[k] * W_e[k * FEAT_D + t];
    // pack feature pairs (t even: [t, t+1]) into one uint of 2 bf16
    float b = __shfl_xor(a, 1);
    if ((t & 1) == 0) RELP[r * 64 + (t >> 1)] = packbf2(a, b);
  } else {
    int i = blockIdx.x - N_RELS;
    T[t] = W_h[i * FEAT_D + t];
    __syncthreads();
    float a = 0.f;
    for (int f = 0; f < FEAT_D; ++f)
      a += T[f] * aggre_W[f * FEAT_D + t];
    WC[i * FEAT_D + t] = a;
  }
}

// ---------- H0 = relu(emb_h @ WC + b) -> bf16 ; also zeroes DEG and ACC ----------
__global__ __launch_bounds__(256)
void h0_kernel(const float* __restrict__ emb_h, const float* __restrict__ WC,
               const float* __restrict__ bias, ushort* __restrict__ H,
               int* __restrict__ deg, float* __restrict__ acc, int nNodes) {
  __shared__ float WT[FEAT_D * INIT_D];
  __shared__ float bs[FEAT_D];
  int t = threadIdx.x;
  {
    int g = blockIdx.x * 256 + t;
    if (g < N_NODES) deg[g] = 0;
    if (g < 2 * FEAT_D) acc[g] = 0.f;
  }
  for (int i = t; i < FEAT_D * INIT_D; i += 256) {
    int k = i >> 7, j = i & 127;
    WT[j * INIT_D + k] = WC[i];
  }
  if (t < FEAT_D) bs[t] = bias[t];
  __syncthreads();
  for (int n = blockIdx.x * 256 + t; n < nNodes; n += gridDim.x * 256) {
    float x[INIT_D];
    const float4* xp = (const float4*)(emb_h + (size_t)n * INIT_D);
#pragma unroll
    for (int q = 0; q < 25; ++q) {
      float4 v = xp[q];
      x[4 * q + 0] = v.x; x[4 * q + 1] = v.y; x[4 * q + 2] = v.z; x[4 * q + 3] = v.w;
    }
    uint2* orow = (uint2*)(H + (size_t)n * FEAT_D);
    for (int j4 = 0; j4 < 32; ++j4) {
      float4 a;
      a.x = bs[4 * j4 + 0]; a.y = bs[4 * j4 + 1];
      a.z = bs[4 * j4 + 2]; a.w = bs[4 * j4 + 3];
      const float4* w0 = (const float4*)&WT[(4 * j4 + 0) * INIT_D];
      const float4* w1 = (const float4*)&WT[(4 * j4 + 1) * INIT_D];
      const float4* w2 = (const float4*)&WT[(4 * j4 + 2) * INIT_D];
      const float4* w3 = (const float4*)&WT[(4 * j4 + 3) * INIT_D];
#pragma unroll
      for (int q = 0; q < 25; ++q) {
        float4 v0 = w0[q], v1 = w1[q], v2 = w2[q], v3 = w3[q];
        a.x = fmaf(x[4*q+0], v0.x, a.x); a.x = fmaf(x[4*q+1], v0.y, a.x);
        a.x = fmaf(x[4*q+2], v0.z, a.x); a.x = fmaf(x[4*q+3], v0.w, a.x);
        a.y = fmaf(x[4*q+0], v1.x, a.y); a.y = fmaf(x[4*q+1], v1.y, a.y);
        a.y = fmaf(x[4*q+2], v1.z, a.y); a.y = fmaf(x[4*q+3], v1.w, a.y);
        a.z = fmaf(x[4*q+0], v2.x, a.z); a.z = fmaf(x[4*q+1], v2.y, a.z);
        a.z = fmaf(x[4*q+2], v2.z, a.z); a.z = fmaf(x[4*q+3], v2.w, a.z);
        a.w = fmaf(x[4*q+0], v3.x, a.w); a.w = fmaf(x[4*q+1], v3.y, a.w);
        a.w = fmaf(x[4*q+2], v3.z, a.w); a.w = fmaf(x[4*q+3], v3.w, a.w);
      }
      a.x = fmaxf(a.x, 0.f); a.y = fmaxf(a.y, 0.f);
      a.z = fmaxf(a.z, 0.f); a.w = fmaxf(a.w, 0.f);
      uint2 pk; pk.x = packbf2(a.x, a.y); pk.y = packbf2(a.z, a.w);
      orow[j4] = pk;
    }
  }
}

// ---------- CSR build: histogram of dst ----------
__global__ __launch_bounds__(256)
void hist_kernel(const int* __restrict__ dst, int* __restrict__ deg, int nEdges) {
  for (int e = blockIdx.x * 256 + threadIdx.x; e < nEdges; e += gridDim.x * 256)
    atomicAdd(&deg[dst[e]], 1);
}

// ---------- CSR build: per-block sums of deg ----------
__global__ __launch_bounds__(256)
void scanA_kernel(const int* __restrict__ deg, int* __restrict__ bsum, int n) {
  __shared__ int red[256];
  int t = threadIdx.x;
  int base = blockIdx.x * SCAN_BLK + t * 4;
  int s = 0;
#pragma unroll
  for (int q = 0; q < 4; ++q) {
    int i = base + q;
    s += (i < n) ? deg[i] : 0;
  }
  red[t] = s;
  __syncthreads();
  for (int off = 128; off > 0; off >>= 1) {
    if (t < off) red[t] += red[t + off];
    __syncthreads();
  }
  if (t == 0) bsum[blockIdx.x] = red[0];
}

// ---------- CSR build: wave-parallel scan of the 98 block sums ----------
__global__ __launch_bounds__(128)
void scanBw_kernel(int* __restrict__ bsum, int nb, int* __restrict__ off) {
  __shared__ int s[128];
  int t = threadIdx.x;
  int v = (t < nb) ? bsum[t] : 0;
  s[t] = v;
  __syncthreads();
  for (int o = 1; o < 128; o <<= 1) {
    int u = (t >= o) ? s[t - o] : 0;
    __syncthreads();
    s[t] += u;
    __syncthreads();
  }
  if (t < nb) bsum[t] = s[t] - v;        // exclusive
  if (t == nb - 1) off[N_NODES] = s[t];  // total
}

// ---------- CSR build: final offsets (exclusive scan) + cursor copy ----------
__global__ __launch_bounds__(256)
void scanC_kernel(const int* __restrict__ deg, const int* __restrict__ bsum,
                  int* __restrict__ off, int* __restrict__ cur, int n) {
  __shared__ int lds[256];
  int t = threadIdx.x;
  int base = blockIdx.x * SCAN_BLK + t * 4;
  int d[4];
  int s = 0;
#pragma unroll
  for (int q = 0; q < 4; ++q) {
    int i = base + q;
    d[q] = (i < n) ? deg[i] : 0;
    s += d[q];
  }
  lds[t] = s;
  __syncthreads();
  for (int o = 1; o < 256; o <<= 1) {
    int v = (t >= o) ? lds[t - o] : 0;
    __syncthreads();
    lds[t] += v;
    __syncthreads();
  }
  int excl = lds[t] - s + bsum[blockIdx.x];
#pragma unroll
  for (int q = 0; q < 4; ++q) {
    int i = base + q;
    if (i < n) {
      off[i] = excl;
      cur[i] = excl;
    }
    excl += d[q];
  }
}

// ---------- CSR build: fill packed edge array ----------
__global__ __launch_bounds__(256)
void fill_kernel(const int* __restrict__ src, const int* __restrict__ dst,
                 const int* __restrict__ et, int* __restrict__ cur,
                 int* __restrict__ epk, int nEdges) {
  for (int e = blockIdx.x * 256 + threadIdx.x; e < nEdges; e += gridDim.x * 256) {
    int d = dst[e];
    int pos = atomicAdd(&cur[d], 1);
    epk[pos] = src[e] | (et[e] << 17);
  }
}

// ---------- gather-mean: bf16 H rows from global, REL from LDS ----------
__global__ __launch_bounds__(256)
void gather_mean_kernel(const int* __restrict__ off, const int* __restrict__ epk,
                        const ushort* __restrict__ H, const uint* __restrict__ RELP,
                        float* __restrict__ MEAN, int doBN, float* __restrict__ acc,
                        int nNodes) {
  __shared__ uint relLds[N_RELS * 64];   // 51,200 B packed bf16 REL
  __shared__ float4 red[4][32];          // 2,048 B (two-round BN reduce)
  const uint2* H2 = (const uint2*)H;
  float4* M4 = (float4*)MEAN;
  int t = threadIdx.x;
  int j = t & 31;
  int slot = t >> 5;
  // stage REL into LDS (coalesced copy, L2-hot source)
  for (int i = t; i < N_RELS * 64; i += 256) relLds[i] = RELP[i];
  __syncthreads();
  float4 s1 = {0.f, 0.f, 0.f, 0.f}, s2 = {0.f, 0.f, 0.f, 0.f};
  for (int n = blockIdx.x * 8 + slot; n < nNodes; n += gridDim.x * 8) {
    int beg = off[n], end = off[n + 1];
    float4 a = {0.f, 0.f, 0.f, 0.f};
    int p = beg;
#pragma unroll 1
    for (; p + 4 <= end; p += 4) {
      int u0 = epk[p + 0];
      int u1 = epk[p + 1];
      int u2 = epk[p + 2];
      int u3 = epk[p + 3];
      uint2 h0 = H2[(size_t)(u0 & 0x1FFFF) * 32 + j];
      uint2 h1 = H2[(size_t)(u1 & 0x1FFFF) * 32 + j];
      uint2 h2 = H2[(size_t)(u2 & 0x1FFFF) * 32 + j];
      uint2 h3 = H2[(size_t)(u3 & 0x1FFFF) * 32 + j];
      uint2 r0 = *(const uint2*)&relLds[(u0 >> 17) * 64 + 2 * j];
      uint2 r1 = *(const uint2*)&relLds[(u1 >> 17) * 64 + 2 * j];
      uint2 r2 = *(const uint2*)&relLds[(u2 >> 17) * 64 + 2 * j];
      uint2 r3 = *(const uint2*)&relLds[(u3 >> 17) * 64 + 2 * j];
      a.x += (bf_lo(h0.x) + bf_lo(r0.x)) + (bf_lo(h1.x) + bf_lo(r1.x)) +
             (bf_lo(h2.x) + bf_lo(r2.x)) + (bf_lo(h3.x) + bf_lo(r3.x));
      a.y += (bf_hi(h0.x) + bf_hi(r0.x)) + (bf_hi(h1.x) + bf_hi(r1.x)) +
             (bf_hi(h2.x) + bf_hi(r2.x)) + (bf_hi(h3.x) + bf_hi(r3.x));
      a.z += (bf_lo(h0.y) + bf_lo(r0.y)) + (bf_lo(h1.y) + bf_lo(r1.y)) +
             (bf_lo(h2.y) + bf_lo(r2.y)) + (bf_lo(h3.y) + bf_lo(r3.y));
      a.w += (bf_hi(h0.y) + bf_hi(r0.y)) + (bf_hi(h1.y) + bf_hi(r1.y)) +
             (bf_hi(h2.y) + bf_hi(r2.y)) + (bf_hi(h3.y) + bf_hi(r3.y));
    }
#pragma unroll 1
    for (; p < end; ++p) {
      int u = epk[p];
      uint2 hv = H2[(size_t)(u & 0x1FFFF) * 32 + j];
      uint2 rv = *(const uint2*)&relLds[(u >> 17) * 64 + 2 * j];
      a.x += bf_lo(hv.x) + bf_lo(rv.x); a.y += bf_hi(hv.x) + bf_hi(rv.x);
      a.z += bf_lo(hv.y) + bf_lo(rv.y); a.w += bf_hi(hv.y) + bf_hi(rv.y);
    }
    float rd = (end > beg) ? 1.f / (float)(end - beg) : 0.f;
    a.x *= rd; a.y *= rd; a.z *= rd; a.w *= rd;
    M4[(size_t)n * 32 + j] = a;
    if (doBN) {
      s1.x += a.x; s1.y += a.y; s1.z += a.z; s1.w += a.w;
      s2.x += a.x * a.x; s2.y += a.y * a.y;
      s2.z += a.z * a.z; s2.w += a.w * a.w;
    }
  }
  if (doBN) {
    // combine the two slots within each wave (lanes xor 32)
    s1.x += __shfl_xor(s1.x, 32); s1.y += __shfl_xor(s1.y, 32);
    s1.z += __shfl_xor(s1.z, 32); s1.w += __shfl_xor(s1.w, 32);
    s2.x += __shfl_xor(s2.x, 32); s2.y += __shfl_xor(s2.y, 32);
    s2.z += __shfl_xor(s2.z, 32); s2.w += __shfl_xor(s2.w, 32);
    int w = t >> 6, lane = t & 63;
    __syncthreads();
    if (lane < 32) red[w][lane] = s1;
    __syncthreads();
    if (t < 32) {
      float4 a1 = red[0][t];
      float4 b1 = red[1][t], c1 = red[2][t], d1 = red[3][t];
      a1.x += b1.x + c1.x + d1.x; a1.y += b1.y + c1.y + d1.y;
      a1.z += b1.z + c1.z + d1.z; a1.w += b1.w + c1.w + d1.w;
      atomicAdd(&acc[4 * t + 0], a1.x);
      atomicAdd(&acc[4 * t + 1], a1.y);
      atomicAdd(&acc[4 * t + 2], a1.z);
      atomicAdd(&acc[4 * t + 3], a1.w);
    }
    __syncthreads();
    if (lane < 32) red[w][lane] = s2;
    __syncthreads();
    if (t < 32) {
      float4 a2 = red[0][t];
      float4 b2 = red[1][t], c2 = red[2][t], d2 = red[3][t];
      a2.x += b2.x + c2.x + d2.x; a2.y += b2.y + c2.y + d2.y;
      a2.z += b2.z + c2.z + d2.z; a2.w += b2.w + c2.w + d2.w;
      atomicAdd(&acc[FEAT_D + 4 * t + 0], a2.x);
      atomicAdd(&acc[FEAT_D + 4 * t + 1], a2.y);
      atomicAdd(&acc[FEAT_D + 4 * t + 2], a2.z);
      atomicAdd(&acc[FEAT_D + 4 * t + 3], a2.w);
    }
  }
}

// ---------- H1 = relu(MEAN @ aggre_W + b) -> bf16 ; nt MEAN loads ; zeroes DEG ----------
__global__ __launch_bounds__(256)
void h1_kernel(const float* __restrict__ mean, const float* __restrict__ W,
               const float* __restrict__ bias, ushort* __restrict__ H,
               int* __restrict__ deg, int nNodes) {
  __shared__ float WT[FEAT_D * FEAT_D];
  __shared__ float bs[FEAT_D];
  int t = threadIdx.x;
  {
    int g = blockIdx.x * 256 + t;
    if (g < N_NODES) deg[g] = 0;
  }
  for (int i = t; i < FEAT_D * FEAT_D; i += 256) {
    int k = i >> 7, j = i & 127;
    WT[j * FEAT_D + k] = W[i];
  }
  if (t < FEAT_D) bs[t] = bias[t];
  __syncthreads();
  for (int n = blockIdx.x * 256 + t; n < nNodes; n += gridDim.x * 256) {
    float x[FEAT_D];
    const f4v* xp = (const f4v*)(mean + (size_t)n * FEAT_D);
#pragma unroll
    for (int q = 0; q < 32; ++q) {
      f4v v = __builtin_nontemporal_load(xp + q);
      x[4 * q + 0] = v[0]; x[4 * q + 1] = v[1];
      x[4 * q + 2] = v[2]; x[4 * q + 3] = v[3];
    }
    uint2* orow = (uint2*)(H + (size_t)n * FEAT_D);
    for (int j4 = 0; j4 < 32; ++j4) {
      float4 a;
      a.x = bs[4 * j4 + 0]; a.y = bs[4 * j4 + 1];
      a.z = bs[4 * j4 + 2]; a.w = bs[4 * j4 + 3];
      const float4* w0 = (const float4*)&WT[(4 * j4 + 0) * FEAT_D];
      const float4* w1 = (const float4*)&WT[(4 * j4 + 1) * FEAT_D];
      const float4* w2 = (const float4*)&WT[(4 * j4 + 2) * FEAT_D];
      const float4* w3 = (const float4*)&WT[(4 * j4 + 3) * FEAT_D];
#pragma unroll
      for (int q = 0; q < 32; ++q) {
        float4 v0 = w0[q], v1 = w1[q], v2 = w2[q], v3 = w3[q];
        a.x = fmaf(x[4*q+0], v0.x, a.x); a.x = fmaf(x[4*q+1], v0.y, a.x);
        a.x = fmaf(x[4*q+2], v0.z, a.x); a.x = fmaf(x[4*q+3], v0.w, a.x);
        a.y = fmaf(x[4*q+0], v1.x, a.y); a.y = fmaf(x[4*q+1], v1.y, a.y);
        a.y = fmaf(x[4*q+2], v1.z, a.y); a.y = fmaf(x[4*q+3], v1.w, a.y);
        a.z = fmaf(x[4*q+0], v2.x, a.z); a.z = fmaf(x[4*q+1], v2.y, a.z);
        a.z = fmaf(x[4*q+2], v2.z, a.z); a.z = fmaf(x[4*q+3], v2.w, a.z);
        a.w = fmaf(x[4*q+0], v3.x, a.w); a.w = fmaf(x[4*q+1], v3.y, a.w);
        a.w = fmaf(x[4*q+2], v3.z, a.w); a.w = fmaf(x[4*q+3], v3.w, a.w);
      }
      a.x = fmaxf(a.x, 0.f); a.y = fmaxf(a.y, 0.f);
      a.z = fmaxf(a.z, 0.f); a.w = fmaxf(a.w, 0.f);
      uint2 pk; pk.x = packbf2(a.x, a.y); pk.y = packbf2(a.z, a.w);
      orow[j4] = pk;
    }
  }
}

// ---------- final: BN -> relu -> MLP 128->64->32->50 ; one node per thread ----------
__global__ __launch_bounds__(256)
void final_kernel(const float* __restrict__ mean, const float* __restrict__ acc,
                  const float* __restrict__ gamma, const float* __restrict__ beta,
                  const float* __restrict__ fc0w, const float* __restrict__ fc0b,
                  const float* __restrict__ fc1w, const float* __restrict__ fc1b,
                  const float* __restrict__ fc2w, const float* __restrict__ fc2b,
                  float* __restrict__ out, int nNodes) {
  __shared__ float W0T[64 * FEAT_D];
  __shared__ float W1L[64 * 32];
  __shared__ float W2T[N_CLS * 32];
  __shared__ float sc[FEAT_D], sh[FEAT_D];
  __shared__ float b0[64], b1[32], b2[N_CLS];
  int t = threadIdx.x;
  for (int i = t; i < 64 * FEAT_D; i += 256) {
    int k = i >> 6, j = i & 63;
    W0T[j * FEAT_D + k] = fc0w[i];
  }
  for (int i = t; i < 64 * 32; i += 256) W1L[i] = fc1w[i];
  for (int i = t; i < 32 * N_CLS; i += 256) {
    int jj = i / N_CLS, c = i % N_CLS;
    W2T[c * 32 + jj] = fc2w[i];
  }
  if (t < FEAT_D) {
    float m = acc[t] * (1.f / (float)N_NODES);
    float v = acc[FEAT_D + t] * (1.f / (float)N_NODES) - m * m;
    float r = rsqrtf(v + BN_EPS);
    float g = gamma[t];
    sc[t] = r * g;
    sh[t] = beta[t] - m * r * g;
  }
  if (t < 64) b0[t] = fc0b[t];
  if (t < 32) b1[t] = fc1b[t];
  if (t < N_CLS) b2[t] = fc2b[t];
  __syncthreads();
  for (int n = blockIdx.x * 256 + t; n < nNodes; n += gridDim.x * 256) {
    float x[FEAT_D];
    const f4v* xp = (const f4v*)(mean + (size_t)n * FEAT_D);
#pragma unroll
    for (int q = 0; q < 32; ++q) {
      f4v v = __builtin_nontemporal_load(xp + q);
      x[4*q+0] = fmaxf(fmaf(v[0], sc[4*q+0], sh[4*q+0]), 0.f);
      x[4*q+1] = fmaxf(fmaf(v[1], sc[4*q+1], sh[4*q+1]), 0.f);
      x[4*q+2] = fmaxf(fmaf(v[2], sc[4*q+2], sh[4*q+2]), 0.f);
      x[4*q+3] = fmaxf(fmaf(v[3], sc[4*q+3], sh[4*q+3]), 0.f);
    }
    float acc2[32];
#pragma unroll
    for (int jj = 0; jj < 32; ++jj) acc2[jj] = b1[jj];
    for (int j = 0; j < 64; ++j) {
      float a = b0[j];
      const float4* w = (const float4*)&W0T[j * FEAT_D];
#pragma unroll
      for (int q = 0; q < 32; ++q) {
        float4 v = w[q];
        a = fmaf(x[4*q+0], v.x, a); a = fmaf(x[4*q+1], v.y, a);
        a = fmaf(x[4*q+2], v.z, a); a = fmaf(x[4*q+3], v.w, a);
      }
      float h = fmaxf(a, 0.f);
      const float4* w1 = (const float4*)&W1L[j * 32];
#pragma unroll
      for (int q = 0; q < 8; ++q) {
        float4 v = w1[q];
        acc2[4*q+0] = fmaf(h, v.x, acc2[4*q+0]);
        acc2[4*q+1] = fmaf(h, v.y, acc2[4*q+1]);
        acc2[4*q+2] = fmaf(h, v.z, acc2[4*q+2]);
        acc2[4*q+3] = fmaf(h, v.w, acc2[4*q+3]);
      }
    }
    float h2[32];
#pragma unroll
    for (int jj = 0; jj < 32; ++jj) h2[jj] = fmaxf(acc2[jj], 0.f);
    float* orow = out + (size_t)n * N_CLS;
    for (int cc = 0; cc < N_CLS; ++cc) {
      float a = b2[cc];
      const float4* w = (const float4*)&W2T[cc * 32];
#pragma unroll
      for (int q = 0; q < 8; ++q) {
        float4 v = w[q];
        a = fmaf(h2[4*q+0], v.x, a); a = fmaf(h2[4*q+1], v.y, a);
        a = fmaf(h2[4*q+2], v.z, a); a = fmaf(h2[4*q+3], v.w, a);
      }
      orow[cc] = a;
    }
  }
}

extern "C" void kernel_launch(void* const* d_in, const int* in_sizes, int n_in,
                              void* d_out, int out_size, void* d_ws, size_t ws_size,
                              hipStream_t stream) {
  const int* edge_src = (const int*)d_in[0];
  const int* edge_dst = (const int*)d_in[1];
  const int* edge_type = (const int*)d_in[2];
  const float* emb_h = (const float*)d_in[3];
  const float* emb_e = (const float*)d_in[4];
  const float* rel_wt = (const float*)d_in[5];
  const float* W_h_init = (const float*)d_in[6];
  const float* W_e_init = (const float*)d_in[7];
  const float* aggre_W = (const float*)d_in[8];
  const float* aggre_b = (const float*)d_in[9];
  const float* bn_gamma = (const float*)d_in[10];
  const float* bn_beta = (const float*)d_in[11];
  const float* fc0_w = (const float*)d_in[12];
  const float* fc0_b = (const float*)d_in[13];
  const float* fc1_w = (const float*)d_in[14];
  const float* fc1_b = (const float*)d_in[15];
  const float* fc2_w = (const float*)d_in[16];
  const float* fc2_b = (const float*)d_in[17];
  float* out = (float*)d_out;

  // ---- workspace layout (bytes): ~77 MB ----
  char* ws = (char*)d_ws;
  uint*   RELP = (uint*)(ws);                     // 200*64*4 = 51,200
  float*  WC   = (float*)(ws + 51200);            // 51,200
  ushort* H    = (ushort*)(ws + 102400);          // 25,600,000
  float*  MEAN = (float*)(ws + 25702400);         // 51,200,000
  float*  ACC  = (float*)(ws + 76902400);         // 1,024

  // ---- CSR scratch lives in d_out (20 MB); final_kernel overwrites it last ----
  char* ob = (char*)d_out;
  int* EPK  = (int*)(ob);                        // 2,000,000
  int* DEG  = (int*)(ob + 2000000);              // 400,000
  int* OFF  = (int*)(ob + 2400000);              // 400,004
  int* CUR  = (int*)(ob + 2800004);              // 400,004
  int* BSUM = (int*)(ob + 3200008);              // 392

  const int NODE_BLOCKS = (N_NODES + 255) / 256;  // 391
  const int GATHER_BLOCKS = 2048;

  relwc_kernel<<<N_RELS + INIT_D, 128, 0, stream>>>(rel_wt, emb_e, W_e_init, RELP,
                                                    W_h_init, aggre_W, WC);
  h0_kernel<<<NODE_BLOCKS, 256, 0, stream>>>(emb_h, WC, aggre_b, H, DEG, ACC,
                                             N_NODES);

  // ---- layer 0: build CSR (DEG zeroed by h0) and gather ----
  hist_kernel<<<1024, 256, 0, stream>>>(edge_dst, DEG, N_EDGES);
  scanA_kernel<<<NB_SCAN, 256, 0, stream>>>(DEG, BSUM, N_NODES);
  scanBw_kernel<<<1, 128, 0, stream>>>(BSUM, NB_SCAN, OFF);
  scanC_kernel<<<NB_SCAN, 256, 0, stream>>>(DEG, BSUM, OFF, CUR, N_NODES);
  fill_kernel<<<1024, 256, 0, stream>>>(edge_src, edge_dst, edge_type, CUR, EPK,
                                        N_EDGES);
  gather_mean_kernel<<<GATHER_BLOCKS, 256, 0, stream>>>(OFF, EPK, H, RELP, MEAN, 0,
                                                        ACC, N_NODES);

  h1_kernel<<<NODE_BLOCKS, 256, 0, stream>>>(MEAN, aggre_W, aggre_b, H, DEG,
                                             N_NODES);

  // ---- layer 1: build CSR (DEG zeroed by h1) and gather (+BN stats) ----
  hist_kernel<<<1024, 256, 0, stream>>>(edge_dst + N_EDGES, DEG, N_EDGES);
  scanA_kernel<<<NB_SCAN, 256, 0, stream>>>(DEG, BSUM, N_NODES);
  scanBw_kernel<<<1, 128, 0, stream>>>(BSUM, NB_SCAN, OFF);
  scanC_kernel<<<NB_SCAN, 256, 0, stream>>>(DEG, BSUM, OFF, CUR, N_NODES);
  fill_kernel<<<1024, 256, 0, stream>>>(edge_src + N_EDGES, edge_dst + N_EDGES,
                                        edge_type + N_EDGES, CUR, EPK, N_EDGES);
  gather_mean_kernel<<<GATHER_BLOCKS, 256, 0, stream>>>(OFF, EPK, H, RELP, MEAN, 1,
                                                        ACC, N_NODES);

  final_kernel<<<NODE_BLOCKS, 256, 0, stream>>>(MEAN, ACC, bn_gamma, bn_beta,
                                                fc0_w, fc0_b, fc1_w, fc1_b,
                                                fc2_w, fc2_b, out, N_NODES);
}

// Round 9
// 707.602 us; speedup vs baseline: 1.4554x; 1.1708x over previous
//
#include <hip/hip_runtime.h>
#include <cstdint>
#include <cstddef>

#define N_NODES 100000
#define N_EDGES 500000
#define N_RELS  200
#define N_BASE  50
#define INIT_D  100
#define FEAT_D  128
#define N_CLS   50
#define BN_EPS  1e-5f

#define SCAN_BLK 1024
#define NB_SCAN  ((N_NODES + SCAN_BLK - 1) / SCAN_BLK)   // 98

typedef unsigned int uint;
typedef unsigned short ushort;

// bf16 helpers (RNE pack, cheap unpack)
__device__ inline uint packbf2(float a, float b) {
  uint ua = __float_as_uint(a); ua = (ua + 0x7fffu + ((ua >> 16) & 1u)) >> 16;
  uint ub = __float_as_uint(b); ub = (ub + 0x7fffu + ((ub >> 16) & 1u)) >> 16;
  return ua | (ub << 16);
}
__device__ inline float bf_lo(uint u) { return __uint_as_float(u << 16); }
__device__ inline float bf_hi(uint u) { return __uint_as_float(u & 0xffff0000u); }

// ---------- fused: blocks 0..199 -> REL rows (fp32); 200..299 -> WC rows ----------
__global__ __launch_bounds__(128)
void relwc_kernel(const float* __restrict__ rel_wt, const float* __restrict__ emb_e,
                  const float* __restrict__ W_e, float* __restrict__ REL,
                  const float* __restrict__ W_h, const float* __restrict__ aggre_W,
                  float* __restrict__ WC) {
  __shared__ float T[FEAT_D];
  int t = threadIdx.x;
  if (blockIdx.x < N_RELS) {
    int r = blockIdx.x;
    if (t < INIT_D) {
      float a = 0.f;
      for (int b = 0; b < N_BASE; ++b)
        a += rel_wt[r * N_BASE + b] * emb_e[b * INIT_D + t];
      T[t] = a;
    }
    __syncthreads();
    float a = 0.f;
    for (int k = 0; k < INIT_D; ++k)
      a += T[k] * W_e[k * FEAT_D + t];
    REL[r * FEAT_D + t] = a;
  } else {
    int i = blockIdx.x - N_RELS;
    T[t] = W_h[i * FEAT_D + t];
    __syncthreads();
    float a = 0.f;
    for (int f = 0; f < FEAT_D; ++f)
      a += T[f] * aggre_W[f * FEAT_D + t];
    WC[i * FEAT_D + t] = a;
  }
}

// ---------- H0 = relu(emb_h @ WC + b) -> bf16 ; also zeroes DEG and ACC ----------
__global__ __launch_bounds__(256)
void h0_kernel(const float* __restrict__ emb_h, const float* __restrict__ WC,
               const float* __restrict__ bias, ushort* __restrict__ H,
               int* __restrict__ deg, float* __restrict__ acc, int nNodes) {
  __shared__ float WT[FEAT_D * INIT_D];
  __shared__ float bs[FEAT_D];
  int t = threadIdx.x;
  {
    int g = blockIdx.x * 256 + t;
    if (g < N_NODES) deg[g] = 0;
    if (g < 2 * FEAT_D) acc[g] = 0.f;
  }
  for (int i = t; i < FEAT_D * INIT_D; i += 256) {
    int k = i >> 7, j = i & 127;
    WT[j * INIT_D + k] = WC[i];
  }
  if (t < FEAT_D) bs[t] = bias[t];
  __syncthreads();
  for (int n = blockIdx.x * 256 + t; n < nNodes; n += gridDim.x * 256) {
    float x[INIT_D];
    const float4* xp = (const float4*)(emb_h + (size_t)n * INIT_D);
#pragma unroll
    for (int q = 0; q < 25; ++q) {
      float4 v = xp[q];
      x[4 * q + 0] = v.x; x[4 * q + 1] = v.y; x[4 * q + 2] = v.z; x[4 * q + 3] = v.w;
    }
    uint2* orow = (uint2*)(H + (size_t)n * FEAT_D);
    for (int j4 = 0; j4 < 32; ++j4) {
      float4 a;
      a.x = bs[4 * j4 + 0]; a.y = bs[4 * j4 + 1];
      a.z = bs[4 * j4 + 2]; a.w = bs[4 * j4 + 3];
      const float4* w0 = (const float4*)&WT[(4 * j4 + 0) * INIT_D];
      const float4* w1 = (const float4*)&WT[(4 * j4 + 1) * INIT_D];
      const float4* w2 = (const float4*)&WT[(4 * j4 + 2) * INIT_D];
      const float4* w3 = (const float4*)&WT[(4 * j4 + 3) * INIT_D];
#pragma unroll
      for (int q = 0; q < 25; ++q) {
        float4 v0 = w0[q], v1 = w1[q], v2 = w2[q], v3 = w3[q];
        a.x = fmaf(x[4*q+0], v0.x, a.x); a.x = fmaf(x[4*q+1], v0.y, a.x);
        a.x = fmaf(x[4*q+2], v0.z, a.x); a.x = fmaf(x[4*q+3], v0.w, a.x);
        a.y = fmaf(x[4*q+0], v1.x, a.y); a.y = fmaf(x[4*q+1], v1.y, a.y);
        a.y = fmaf(x[4*q+2], v1.z, a.y); a.y = fmaf(x[4*q+3], v1.w, a.y);
        a.z = fmaf(x[4*q+0], v2.x, a.z); a.z = fmaf(x[4*q+1], v2.y, a.z);
        a.z = fmaf(x[4*q+2], v2.z, a.z); a.z = fmaf(x[4*q+3], v2.w, a.z);
        a.w = fmaf(x[4*q+0], v3.x, a.w); a.w = fmaf(x[4*q+1], v3.y, a.w);
        a.w = fmaf(x[4*q+2], v3.z, a.w); a.w = fmaf(x[4*q+3], v3.w, a.w);
      }
      a.x = fmaxf(a.x, 0.f); a.y = fmaxf(a.y, 0.f);
      a.z = fmaxf(a.z, 0.f); a.w = fmaxf(a.w, 0.f);
      uint2 pk; pk.x = packbf2(a.x, a.y); pk.y = packbf2(a.z, a.w);
      orow[j4] = pk;
    }
  }
}

// ---------- CSR build: histogram of dst ----------
__global__ __launch_bounds__(256)
void hist_kernel(const int* __restrict__ dst, int* __restrict__ deg, int nEdges) {
  for (int e = blockIdx.x * 256 + threadIdx.x; e < nEdges; e += gridDim.x * 256)
    atomicAdd(&deg[dst[e]], 1);
}

// ---------- CSR build: per-block sums of deg ----------
__global__ __launch_bounds__(256)
void scanA_kernel(const int* __restrict__ deg, int* __restrict__ bsum, int n) {
  __shared__ int red[256];
  int t = threadIdx.x;
  int base = blockIdx.x * SCAN_BLK + t * 4;
  int s = 0;
#pragma unroll
  for (int q = 0; q < 4; ++q) {
    int i = base + q;
    s += (i < n) ? deg[i] : 0;
  }
  red[t] = s;
  __syncthreads();
  for (int off = 128; off > 0; off >>= 1) {
    if (t < off) red[t] += red[t + off];
    __syncthreads();
  }
  if (t == 0) bsum[blockIdx.x] = red[0];
}

// ---------- CSR build: wave-parallel scan of the 98 block sums ----------
__global__ __launch_bounds__(128)
void scanBw_kernel(int* __restrict__ bsum, int nb, int* __restrict__ off) {
  __shared__ int s[128];
  int t = threadIdx.x;
  int v = (t < nb) ? bsum[t] : 0;
  s[t] = v;
  __syncthreads();
  for (int o = 1; o < 128; o <<= 1) {
    int u = (t >= o) ? s[t - o] : 0;
    __syncthreads();
    s[t] += u;
    __syncthreads();
  }
  if (t < nb) bsum[t] = s[t] - v;        // exclusive
  if (t == nb - 1) off[N_NODES] = s[t];  // total
}

// ---------- CSR build: final offsets (exclusive scan) + cursor copy ----------
__global__ __launch_bounds__(256)
void scanC_kernel(const int* __restrict__ deg, const int* __restrict__ bsum,
                  int* __restrict__ off, int* __restrict__ cur, int n) {
  __shared__ int lds[256];
  int t = threadIdx.x;
  int base = blockIdx.x * SCAN_BLK + t * 4;
  int d[4];
  int s = 0;
#pragma unroll
  for (int q = 0; q < 4; ++q) {
    int i = base + q;
    d[q] = (i < n) ? deg[i] : 0;
    s += d[q];
  }
  lds[t] = s;
  __syncthreads();
  for (int o = 1; o < 256; o <<= 1) {
    int v = (t >= o) ? lds[t - o] : 0;
    __syncthreads();
    lds[t] += v;
    __syncthreads();
  }
  int excl = lds[t] - s + bsum[blockIdx.x];
#pragma unroll
  for (int q = 0; q < 4; ++q) {
    int i = base + q;
    if (i < n) {
      off[i] = excl;
      cur[i] = excl;
    }
    excl += d[q];
  }
}

// ---------- CSR build: fill packed edge array ----------
__global__ __launch_bounds__(256)
void fill_kernel(const int* __restrict__ src, const int* __restrict__ dst,
                 const int* __restrict__ et, int* __restrict__ cur,
                 int* __restrict__ epk, int nEdges) {
  for (int e = blockIdx.x * 256 + threadIdx.x; e < nEdges; e += gridDim.x * 256) {
    int d = dst[e];
    int pos = atomicAdd(&cur[d], 1);
    epk[pos] = src[e] | (et[e] << 17);
  }
}

// ---------- gather-mean over bf16 H rows, fp32 REL + accum (R5-proven form) ----------
__global__ __launch_bounds__(256)
void gather_mean_kernel(const int* __restrict__ off, const int* __restrict__ epk,
                        const ushort* __restrict__ H, const float* __restrict__ REL,
                        float* __restrict__ MEAN, int doBN, float* __restrict__ acc,
                        int nNodes) {
  const uint2* H2 = (const uint2*)H;
  const float4* R4 = (const float4*)REL;
  float4* M4 = (float4*)MEAN;
  int t = threadIdx.x;
  int j = t & 31;
  int slot = t >> 5;
  float4 s1 = {0.f, 0.f, 0.f, 0.f}, s2 = {0.f, 0.f, 0.f, 0.f};
  for (int n = blockIdx.x * 8 + slot; n < nNodes; n += gridDim.x * 8) {
    int beg = off[n], end = off[n + 1];
    float4 a = {0.f, 0.f, 0.f, 0.f};
    int p = beg;
#pragma unroll 1
    for (; p + 4 <= end; p += 4) {
      int u0 = epk[p + 0];
      int u1 = epk[p + 1];
      int u2 = epk[p + 2];
      int u3 = epk[p + 3];
      uint2 h0 = H2[(size_t)(u0 & 0x1FFFF) * 32 + j];
      uint2 h1 = H2[(size_t)(u1 & 0x1FFFF) * 32 + j];
      uint2 h2 = H2[(size_t)(u2 & 0x1FFFF) * 32 + j];
      uint2 h3 = H2[(size_t)(u3 & 0x1FFFF) * 32 + j];
      float4 r0 = R4[(u0 >> 17) * 32 + j];
      float4 r1 = R4[(u1 >> 17) * 32 + j];
      float4 r2 = R4[(u2 >> 17) * 32 + j];
      float4 r3 = R4[(u3 >> 17) * 32 + j];
      a.x += (bf_lo(h0.x) + r0.x) + (bf_lo(h1.x) + r1.x) +
             (bf_lo(h2.x) + r2.x) + (bf_lo(h3.x) + r3.x);
      a.y += (bf_hi(h0.x) + r0.y) + (bf_hi(h1.x) + r1.y) +
             (bf_hi(h2.x) + r2.y) + (bf_hi(h3.x) + r3.y);
      a.z += (bf_lo(h0.y) + r0.z) + (bf_lo(h1.y) + r1.z) +
             (bf_lo(h2.y) + r2.z) + (bf_lo(h3.y) + r3.z);
      a.w += (bf_hi(h0.y) + r0.w) + (bf_hi(h1.y) + r1.w) +
             (bf_hi(h2.y) + r2.w) + (bf_hi(h3.y) + r3.w);
    }
#pragma unroll 1
    for (; p < end; ++p) {
      int u = epk[p];
      uint2 hv = H2[(size_t)(u & 0x1FFFF) * 32 + j];
      float4 rv = R4[(u >> 17) * 32 + j];
      a.x += bf_lo(hv.x) + rv.x; a.y += bf_hi(hv.x) + rv.y;
      a.z += bf_lo(hv.y) + rv.z; a.w += bf_hi(hv.y) + rv.w;
    }
    float rd = (end > beg) ? 1.f / (float)(end - beg) : 0.f;
    a.x *= rd; a.y *= rd; a.z *= rd; a.w *= rd;
    M4[(size_t)n * 32 + j] = a;
    if (doBN) {
      s1.x += a.x; s1.y += a.y; s1.z += a.z; s1.w += a.w;
      s2.x += a.x * a.x; s2.y += a.y * a.y;
      s2.z += a.z * a.z; s2.w += a.w * a.w;
    }
  }
  if (doBN) {
    __shared__ float4 r1[8][32], r2[8][32];
    r1[slot][j] = s1;
    r2[slot][j] = s2;
    __syncthreads();
    if (slot == 0) {
      float4 a1 = r1[0][j], a2 = r2[0][j];
#pragma unroll
      for (int k = 1; k < 8; ++k) {
        float4 b1 = r1[k][j], b2 = r2[k][j];
        a1.x += b1.x; a1.y += b1.y; a1.z += b1.z; a1.w += b1.w;
        a2.x += b2.x; a2.y += b2.y; a2.z += b2.z; a2.w += b2.w;
      }
      atomicAdd(&acc[4 * j + 0], a1.x);
      atomicAdd(&acc[4 * j + 1], a1.y);
      atomicAdd(&acc[4 * j + 2], a1.z);
      atomicAdd(&acc[4 * j + 3], a1.w);
      atomicAdd(&acc[FEAT_D + 4 * j + 0], a2.x);
      atomicAdd(&acc[FEAT_D + 4 * j + 1], a2.y);
      atomicAdd(&acc[FEAT_D + 4 * j + 2], a2.z);
      atomicAdd(&acc[FEAT_D + 4 * j + 3], a2.w);
    }
  }
}

// ---------- H1 = relu(MEAN @ aggre_W + b) -> bf16 ; zeroes DEG ----------
__global__ __launch_bounds__(256)
void h1_kernel(const float* __restrict__ mean, const float* __restrict__ W,
               const float* __restrict__ bias, ushort* __restrict__ H,
               int* __restrict__ deg, int nNodes) {
  __shared__ float WT[FEAT_D * FEAT_D];
  __shared__ float bs[FEAT_D];
  int t = threadIdx.x;
  {
    int g = blockIdx.x * 256 + t;
    if (g < N_NODES) deg[g] = 0;
  }
  for (int i = t; i < FEAT_D * FEAT_D; i += 256) {
    int k = i >> 7, j = i & 127;
    WT[j * FEAT_D + k] = W[i];
  }
  if (t < FEAT_D) bs[t] = bias[t];
  __syncthreads();
  for (int n = blockIdx.x * 256 + t; n < nNodes; n += gridDim.x * 256) {
    float x[FEAT_D];
    const float4* xp = (const float4*)(mean + (size_t)n * FEAT_D);
#pragma unroll
    for (int q = 0; q < 32; ++q) {
      float4 v = xp[q];
      x[4 * q + 0] = v.x; x[4 * q + 1] = v.y;
      x[4 * q + 2] = v.z; x[4 * q + 3] = v.w;
    }
    uint2* orow = (uint2*)(H + (size_t)n * FEAT_D);
    for (int j4 = 0; j4 < 32; ++j4) {
      float4 a;
      a.x = bs[4 * j4 + 0]; a.y = bs[4 * j4 + 1];
      a.z = bs[4 * j4 + 2]; a.w = bs[4 * j4 + 3];
      const float4* w0 = (const float4*)&WT[(4 * j4 + 0) * FEAT_D];
      const float4* w1 = (const float4*)&WT[(4 * j4 + 1) * FEAT_D];
      const float4* w2 = (const float4*)&WT[(4 * j4 + 2) * FEAT_D];
      const float4* w3 = (const float4*)&WT[(4 * j4 + 3) * FEAT_D];
#pragma unroll
      for (int q = 0; q < 32; ++q) {
        float4 v0 = w0[q], v1 = w1[q], v2 = w2[q], v3 = w3[q];
        a.x = fmaf(x[4*q+0], v0.x, a.x); a.x = fmaf(x[4*q+1], v0.y, a.x);
        a.x = fmaf(x[4*q+2], v0.z, a.x); a.x = fmaf(x[4*q+3], v0.w, a.x);
        a.y = fmaf(x[4*q+0], v1.x, a.y); a.y = fmaf(x[4*q+1], v1.y, a.y);
        a.y = fmaf(x[4*q+2], v1.z, a.y); a.y = fmaf(x[4*q+3], v1.w, a.y);
        a.z = fmaf(x[4*q+0], v2.x, a.z); a.z = fmaf(x[4*q+1], v2.y, a.z);
        a.z = fmaf(x[4*q+2], v2.z, a.z); a.z = fmaf(x[4*q+3], v2.w, a.z);
        a.w = fmaf(x[4*q+0], v3.x, a.w); a.w = fmaf(x[4*q+1], v3.y, a.w);
        a.w = fmaf(x[4*q+2], v3.z, a.w); a.w = fmaf(x[4*q+3], v3.w, a.w);
      }
      a.x = fmaxf(a.x, 0.f); a.y = fmaxf(a.y, 0.f);
      a.z = fmaxf(a.z, 0.f); a.w = fmaxf(a.w, 0.f);
      uint2 pk; pk.x = packbf2(a.x, a.y); pk.y = packbf2(a.z, a.w);
      orow[j4] = pk;
    }
  }
}

// ---------- final: BN -> relu -> MLP ; ILP-8 fc0, ILP-4 fc2, padded W0T ----------
#define W0_LD 132   // 128 + 4 pad: 16B-aligned rows, breaks stride-128 bank conflict
__global__ __launch_bounds__(256)
void final_kernel(const float* __restrict__ mean, const float* __restrict__ acc,
                  const float* __restrict__ gamma, const float* __restrict__ beta,
                  const float* __restrict__ fc0w, const float* __restrict__ fc0b,
                  const float* __restrict__ fc1w, const float* __restrict__ fc1b,
                  const float* __restrict__ fc2w, const float* __restrict__ fc2b,
                  float* __restrict__ out, int nNodes) {
  __shared__ float W0T[64 * W0_LD];    // 33,792 B  W0T[j*132+k] = fc0w[k*64+j]
  __shared__ float W1L[64 * 32];       // fc1w as-is
  __shared__ float W2T[N_CLS * 32];    // W2T[c*32+jj] = fc2w[jj*50+c]
  __shared__ float sc[FEAT_D], sh[FEAT_D];
  __shared__ float b0[64], b1[32], b2[N_CLS];
  int t = threadIdx.x;
  for (int i = t; i < 64 * FEAT_D; i += 256) {
    int k = i >> 6, j = i & 63;
    W0T[j * W0_LD + k] = fc0w[i];
  }
  for (int i = t; i < 64 * 32; i += 256) W1L[i] = fc1w[i];
  for (int i = t; i < 32 * N_CLS; i += 256) {
    int jj = i / N_CLS, c = i % N_CLS;
    W2T[c * 32 + jj] = fc2w[i];
  }
  if (t < FEAT_D) {
    float m = acc[t] * (1.f / (float)N_NODES);
    float v = acc[FEAT_D + t] * (1.f / (float)N_NODES) - m * m;
    float r = rsqrtf(v + BN_EPS);
    float g = gamma[t];
    sc[t] = r * g;
    sh[t] = beta[t] - m * r * g;
  }
  if (t < 64) b0[t] = fc0b[t];
  if (t < 32) b1[t] = fc1b[t];
  if (t < N_CLS) b2[t] = fc2b[t];
  __syncthreads();
  for (int n = blockIdx.x * 256 + t; n < nNodes; n += gridDim.x * 256) {
    float x[FEAT_D];
    const float4* xp = (const float4*)(mean + (size_t)n * FEAT_D);
#pragma unroll
    for (int q = 0; q < 32; ++q) {
      float4 v = xp[q];
      x[4*q+0] = fmaxf(fmaf(v.x, sc[4*q+0], sh[4*q+0]), 0.f);
      x[4*q+1] = fmaxf(fmaf(v.y, sc[4*q+1], sh[4*q+1]), 0.f);
      x[4*q+2] = fmaxf(fmaf(v.z, sc[4*q+2], sh[4*q+2]), 0.f);
      x[4*q+3] = fmaxf(fmaf(v.w, sc[4*q+3], sh[4*q+3]), 0.f);
    }
    float acc2[32];
#pragma unroll
    for (int jj = 0; jj < 32; ++jj) acc2[jj] = b1[jj];
    for (int j = 0; j < 64; ++j) {
      const float4* w = (const float4*)&W0T[j * W0_LD];
      float a0 = b0[j], a1 = 0.f, a2 = 0.f, a3 = 0.f;
      float a4 = 0.f, a5 = 0.f, a6 = 0.f, a7 = 0.f;
#pragma unroll
      for (int q = 0; q < 32; q += 8) {
        float4 v0 = w[q + 0];
        a0 = fmaf(x[4*q+ 0], v0.x, a0); a0 = fmaf(x[4*q+ 1], v0.y, a0);
        a0 = fmaf(x[4*q+ 2], v0.z, a0); a0 = fmaf(x[4*q+ 3], v0.w, a0);
        float4 v1 = w[q + 1];
        a1 = fmaf(x[4*q+ 4], v1.x, a1); a1 = fmaf(x[4*q+ 5], v1.y, a1);
        a1 = fmaf(x[4*q+ 6], v1.z, a1); a1 = fmaf(x[4*q+ 7], v1.w, a1);
        float4 v2 = w[q + 2];
        a2 = fmaf(x[4*q+ 8], v2.x, a2); a2 = fmaf(x[4*q+ 9], v2.y, a2);
        a2 = fmaf(x[4*q+10], v2.z, a2); a2 = fmaf(x[4*q+11], v2.w, a2);
        float4 v3 = w[q + 3];
        a3 = fmaf(x[4*q+12], v3.x, a3); a3 = fmaf(x[4*q+13], v3.y, a3);
        a3 = fmaf(x[4*q+14], v3.z, a3); a3 = fmaf(x[4*q+15], v3.w, a3);
        float4 v4 = w[q + 4];
        a4 = fmaf(x[4*q+16], v4.x, a4); a4 = fmaf(x[4*q+17], v4.y, a4);
        a4 = fmaf(x[4*q+18], v4.z, a4); a4 = fmaf(x[4*q+19], v4.w, a4);
        float4 v5 = w[q + 5];
        a5 = fmaf(x[4*q+20], v5.x, a5); a5 = fmaf(x[4*q+21], v5.y, a5);
        a5 = fmaf(x[4*q+22], v5.z, a5); a5 = fmaf(x[4*q+23], v5.w, a5);
        float4 v6 = w[q + 6];
        a6 = fmaf(x[4*q+24], v6.x, a6); a6 = fmaf(x[4*q+25], v6.y, a6);
        a6 = fmaf(x[4*q+26], v6.z, a6); a6 = fmaf(x[4*q+27], v6.w, a6);
        float4 v7 = w[q + 7];
        a7 = fmaf(x[4*q+28], v7.x, a7); a7 = fmaf(x[4*q+29], v7.y, a7);
        a7 = fmaf(x[4*q+30], v7.z, a7); a7 = fmaf(x[4*q+31], v7.w, a7);
      }
      float h = fmaxf(((a0 + a1) + (a2 + a3)) + ((a4 + a5) + (a6 + a7)), 0.f);
      const float4* w1 = (const float4*)&W1L[j * 32];
#pragma unroll
      for (int q = 0; q < 8; ++q) {
        float4 v = w1[q];
        acc2[4*q+0] = fmaf(h, v.x, acc2[4*q+0]);
        acc2[4*q+1] = fmaf(h, v.y, acc2[4*q+1]);
        acc2[4*q+2] = fmaf(h, v.z, acc2[4*q+2]);
        acc2[4*q+3] = fmaf(h, v.w, acc2[4*q+3]);
      }
    }
    float h2[32];
#pragma unroll
    for (int jj = 0; jj < 32; ++jj) h2[jj] = fmaxf(acc2[jj], 0.f);
    float* orow = out + (size_t)n * N_CLS;
    for (int cc = 0; cc < N_CLS; ++cc) {
      const float4* w = (const float4*)&W2T[cc * 32];
      float a0 = b2[cc], a1 = 0.f, a2 = 0.f, a3 = 0.f;
#pragma unroll
      for (int q = 0; q < 8; q += 4) {
        float4 v0 = w[q + 0];
        a0 = fmaf(h2[4*q+ 0], v0.x, a0); a0 = fmaf(h2[4*q+ 1], v0.y, a0);
        a0 = fmaf(h2[4*q+ 2], v0.z, a0); a0 = fmaf(h2[4*q+ 3], v0.w, a0);
        float4 v1 = w[q + 1];
        a1 = fmaf(h2[4*q+ 4], v1.x, a1); a1 = fmaf(h2[4*q+ 5], v1.y, a1);
        a1 = fmaf(h2[4*q+ 6], v1.z, a1); a1 = fmaf(h2[4*q+ 7], v1.w, a1);
        float4 v2 = w[q + 2];
        a2 = fmaf(h2[4*q+ 8], v2.x, a2); a2 = fmaf(h2[4*q+ 9], v2.y, a2);
        a2 = fmaf(h2[4*q+10], v2.z, a2); a2 = fmaf(h2[4*q+11], v2.w, a2);
        float4 v3 = w[q + 3];
        a3 = fmaf(h2[4*q+12], v3.x, a3); a3 = fmaf(h2[4*q+13], v3.y, a3);
        a3 = fmaf(h2[4*q+14], v3.z, a3); a3 = fmaf(h2[4*q+15], v3.w, a3);
      }
      orow[cc] = (a0 + a1) + (a2 + a3);
    }
  }
}

extern "C" void kernel_launch(void* const* d_in, const int* in_sizes, int n_in,
                              void* d_out, int out_size, void* d_ws, size_t ws_size,
                              hipStream_t stream) {
  const int* edge_src = (const int*)d_in[0];
  const int* edge_dst = (const int*)d_in[1];
  const int* edge_type = (const int*)d_in[2];
  const float* emb_h = (const float*)d_in[3];
  const float* emb_e = (const float*)d_in[4];
  const float* rel_wt = (const float*)d_in[5];
  const float* W_h_init = (const float*)d_in[6];
  const float* W_e_init = (const float*)d_in[7];
  const float* aggre_W = (const float*)d_in[8];
  const float* aggre_b = (const float*)d_in[9];
  const float* bn_gamma = (const float*)d_in[10];
  const float* bn_beta = (const float*)d_in[11];
  const float* fc0_w = (const float*)d_in[12];
  const float* fc0_b = (const float*)d_in[13];
  const float* fc1_w = (const float*)d_in[14];
  const float* fc1_b = (const float*)d_in[15];
  const float* fc2_w = (const float*)d_in[16];
  const float* fc2_b = (const float*)d_in[17];
  float* out = (float*)d_out;

  // ---- workspace layout (bytes): ~77 MB ----
  char* ws = (char*)d_ws;
  float*  REL  = (float*)(ws);                    // 102,400
  float*  WC   = (float*)(ws + 102400);           // 51,200
  ushort* H    = (ushort*)(ws + 153600);          // 25,600,000
  float*  MEAN = (float*)(ws + 25753600);         // 51,200,000
  float*  ACC  = (float*)(ws + 76953600);         // 1,024

  // ---- CSR scratch lives in d_out (20 MB); final_kernel overwrites it last ----
  char* ob = (char*)d_out;
  int* EPK  = (int*)(ob);                        // 2,000,000
  int* DEG  = (int*)(ob + 2000000);              // 400,000
  int* OFF  = (int*)(ob + 2400000);              // 400,004
  int* CUR  = (int*)(ob + 2800004);              // 400,004
  int* BSUM = (int*)(ob + 3200008);              // 392

  const int NODE_BLOCKS = (N_NODES + 255) / 256;  // 391
  const int GATHER_BLOCKS = 2048;

  relwc_kernel<<<N_RELS + INIT_D, 128, 0, stream>>>(rel_wt, emb_e, W_e_init, REL,
                                                    W_h_init, aggre_W, WC);
  h0_kernel<<<NODE_BLOCKS, 256, 0, stream>>>(emb_h, WC, aggre_b, H, DEG, ACC,
                                             N_NODES);

  // ---- layer 0: build CSR (DEG zeroed by h0) and gather ----
  hist_kernel<<<1024, 256, 0, stream>>>(edge_dst, DEG, N_EDGES);
  scanA_kernel<<<NB_SCAN, 256, 0, stream>>>(DEG, BSUM, N_NODES);
  scanBw_kernel<<<1, 128, 0, stream>>>(BSUM, NB_SCAN, OFF);
  scanC_kernel<<<NB_SCAN, 256, 0, stream>>>(DEG, BSUM, OFF, CUR, N_NODES);
  fill_kernel<<<1024, 256, 0, stream>>>(edge_src, edge_dst, edge_type, CUR, EPK,
                                        N_EDGES);
  gather_mean_kernel<<<GATHER_BLOCKS, 256, 0, stream>>>(OFF, EPK, H, REL, MEAN, 0,
                                                        ACC, N_NODES);

  h1_kernel<<<NODE_BLOCKS, 256, 0, stream>>>(MEAN, aggre_W, aggre_b, H, DEG,
                                             N_NODES);

  // ---- layer 1: build CSR (DEG zeroed by h1) and gather (+BN stats) ----
  hist_kernel<<<1024, 256, 0, stream>>>(edge_dst + N_EDGES, DEG, N_EDGES);
  scanA_kernel<<<NB_SCAN, 256, 0, stream>>>(DEG, BSUM, N_NODES);
  scanBw_kernel<<<1, 128, 0, stream>>>(BSUM, NB_SCAN, OFF);
  scanC_kernel<<<NB_SCAN, 256, 0, stream>>>(DEG, BSUM, OFF, CUR, N_NODES);
  fill_kernel<<<1024, 256, 0, stream>>>(edge_src + N_EDGES, edge_dst + N_EDGES,
                                        edge_type + N_EDGES, CUR, EPK, N_EDGES);
  gather_mean_kernel<<<GATHER_BLOCKS, 256, 0, stream>>>(OFF, EPK, H, REL, MEAN, 1,
                                                        ACC, N_NODES);

  final_kernel<<<NODE_BLOCKS, 256, 0, stream>>>(MEAN, ACC, bn_gamma, bn_beta,
                                                fc0_w, fc0_b, fc1_w, fc1_b,
                                                fc2_w, fc2_b, out, N_NODES);
}

// Round 10
// 648.046 us; speedup vs baseline: 1.5892x; 1.0919x over previous
//
#include <hip/hip_runtime.h>
#include <cstdint>
#include <cstddef>

#define N_NODES 100000
#define N_EDGES 500000
#define N_RELS  200
#define N_BASE  50
#define INIT_D  100
#define FEAT_D  128
#define N_CLS   50
#define BN_EPS  1e-5f

#define SCAN_BLK 1024
#define NB_SCAN  ((N_NODES + SCAN_BLK - 1) / SCAN_BLK)   // 98

typedef unsigned int uint;
typedef unsigned short ushort;

// bf16 helpers (RNE pack, cheap unpack)
__device__ inline uint packbf2(float a, float b) {
  uint ua = __float_as_uint(a); ua = (ua + 0x7fffu + ((ua >> 16) & 1u)) >> 16;
  uint ub = __float_as_uint(b); ub = (ub + 0x7fffu + ((ub >> 16) & 1u)) >> 16;
  return ua | (ub << 16);
}
__device__ inline float bf_lo(uint u) { return __uint_as_float(u << 16); }
__device__ inline float bf_hi(uint u) { return __uint_as_float(u & 0xffff0000u); }

// ---------- fused: REL rows (blocks 0..199), WC rows (200..299); zeroes DEG+ACC ----------
__global__ __launch_bounds__(128)
void relwc_kernel(const float* __restrict__ rel_wt, const float* __restrict__ emb_e,
                  const float* __restrict__ W_e, float* __restrict__ REL,
                  const float* __restrict__ W_h, const float* __restrict__ aggre_W,
                  float* __restrict__ WC, int* __restrict__ deg,
                  float* __restrict__ acc) {
  __shared__ float T[FEAT_D];
  int t = threadIdx.x;
  // fold in zeroing of DEG (layer-0 histogram target) and ACC
  for (int g = blockIdx.x * 128 + t; g < N_NODES; g += gridDim.x * 128) deg[g] = 0;
  if (blockIdx.x == 0) {
    for (int g = t; g < 2 * FEAT_D; g += 128) acc[g] = 0.f;
  }
  if (blockIdx.x < N_RELS) {
    int r = blockIdx.x;
    if (t < INIT_D) {
      float a = 0.f;
      for (int b = 0; b < N_BASE; ++b)
        a += rel_wt[r * N_BASE + b] * emb_e[b * INIT_D + t];
      T[t] = a;
    }
    __syncthreads();
    float a = 0.f;
    for (int k = 0; k < INIT_D; ++k)
      a += T[k] * W_e[k * FEAT_D + t];
    REL[r * FEAT_D + t] = a;
  } else {
    int i = blockIdx.x - N_RELS;
    T[t] = W_h[i * FEAT_D + t];
    __syncthreads();
    float a = 0.f;
    for (int f = 0; f < FEAT_D; ++f)
      a += T[f] * aggre_W[f * FEAT_D + t];
    WC[i * FEAT_D + t] = a;
  }
}

// ---------- H0 = relu(emb_h @ WC + b) -> bf16 ; tail: histogram of layer-0 dst ----------
__global__ __launch_bounds__(256)
void h0_kernel(const float* __restrict__ emb_h, const float* __restrict__ WC,
               const float* __restrict__ bias, ushort* __restrict__ H,
               const int* __restrict__ dst0, int* __restrict__ deg, int nNodes) {
  __shared__ float WT[FEAT_D * INIT_D];
  __shared__ float bs[FEAT_D];
  int t = threadIdx.x;
  for (int i = t; i < FEAT_D * INIT_D; i += 256) {
    int k = i >> 7, j = i & 127;
    WT[j * INIT_D + k] = WC[i];
  }
  if (t < FEAT_D) bs[t] = bias[t];
  __syncthreads();
  for (int n = blockIdx.x * 256 + t; n < nNodes; n += gridDim.x * 256) {
    float x[INIT_D];
    const float4* xp = (const float4*)(emb_h + (size_t)n * INIT_D);
#pragma unroll
    for (int q = 0; q < 25; ++q) {
      float4 v = xp[q];
      x[4 * q + 0] = v.x; x[4 * q + 1] = v.y; x[4 * q + 2] = v.z; x[4 * q + 3] = v.w;
    }
    uint2* orow = (uint2*)(H + (size_t)n * FEAT_D);
    for (int j4 = 0; j4 < 32; ++j4) {
      float4 a;
      a.x = bs[4 * j4 + 0]; a.y = bs[4 * j4 + 1];
      a.z = bs[4 * j4 + 2]; a.w = bs[4 * j4 + 3];
      const float4* w0 = (const float4*)&WT[(4 * j4 + 0) * INIT_D];
      const float4* w1 = (const float4*)&WT[(4 * j4 + 1) * INIT_D];
      const float4* w2 = (const float4*)&WT[(4 * j4 + 2) * INIT_D];
      const float4* w3 = (const float4*)&WT[(4 * j4 + 3) * INIT_D];
#pragma unroll
      for (int q = 0; q < 25; ++q) {
        float4 v0 = w0[q], v1 = w1[q], v2 = w2[q], v3 = w3[q];
        a.x = fmaf(x[4*q+0], v0.x, a.x); a.x = fmaf(x[4*q+1], v0.y, a.x);
        a.x = fmaf(x[4*q+2], v0.z, a.x); a.x = fmaf(x[4*q+3], v0.w, a.x);
        a.y = fmaf(x[4*q+0], v1.x, a.y); a.y = fmaf(x[4*q+1], v1.y, a.y);
        a.y = fmaf(x[4*q+2], v1.z, a.y); a.y = fmaf(x[4*q+3], v1.w, a.y);
        a.z = fmaf(x[4*q+0], v2.x, a.z); a.z = fmaf(x[4*q+1], v2.y, a.z);
        a.z = fmaf(x[4*q+2], v2.z, a.z); a.z = fmaf(x[4*q+3], v2.w, a.z);
        a.w = fmaf(x[4*q+0], v3.x, a.w); a.w = fmaf(x[4*q+1], v3.y, a.w);
        a.w = fmaf(x[4*q+2], v3.z, a.w); a.w = fmaf(x[4*q+3], v3.w, a.w);
      }
      a.x = fmaxf(a.x, 0.f); a.y = fmaxf(a.y, 0.f);
      a.z = fmaxf(a.z, 0.f); a.w = fmaxf(a.w, 0.f);
      uint2 pk; pk.x = packbf2(a.x, a.y); pk.y = packbf2(a.z, a.w);
      orow[j4] = pk;
    }
  }
  // tail: layer-0 dst histogram (DEG pre-zeroed by relwc_kernel)
  for (int e = blockIdx.x * 256 + t; e < N_EDGES; e += gridDim.x * 256)
    atomicAdd(&deg[dst0[e]], 1);
}

// ---------- CSR build: per-block sums of deg ----------
__global__ __launch_bounds__(256)
void scanA_kernel(const int* __restrict__ deg, int* __restrict__ bsum, int n) {
  __shared__ int red[256];
  int t = threadIdx.x;
  int base = blockIdx.x * SCAN_BLK + t * 4;
  int s = 0;
#pragma unroll
  for (int q = 0; q < 4; ++q) {
    int i = base + q;
    s += (i < n) ? deg[i] : 0;
  }
  red[t] = s;
  __syncthreads();
  for (int off = 128; off > 0; off >>= 1) {
    if (t < off) red[t] += red[t + off];
    __syncthreads();
  }
  if (t == 0) bsum[blockIdx.x] = red[0];
}

// ---------- CSR build: wave-parallel scan of the 98 block sums ----------
__global__ __launch_bounds__(128)
void scanBw_kernel(int* __restrict__ bsum, int nb, int* __restrict__ off) {
  __shared__ int s[128];
  int t = threadIdx.x;
  int v = (t < nb) ? bsum[t] : 0;
  s[t] = v;
  __syncthreads();
  for (int o = 1; o < 128; o <<= 1) {
    int u = (t >= o) ? s[t - o] : 0;
    __syncthreads();
    s[t] += u;
    __syncthreads();
  }
  if (t < nb) bsum[t] = s[t] - v;        // exclusive
  if (t == nb - 1) off[N_NODES] = s[t];  // total
}

// ---------- CSR build: final offsets (exclusive scan) + cursor copy ----------
__global__ __launch_bounds__(256)
void scanC_kernel(const int* __restrict__ deg, const int* __restrict__ bsum,
                  int* __restrict__ off, int* __restrict__ cur, int n) {
  __shared__ int lds[256];
  int t = threadIdx.x;
  int base = blockIdx.x * SCAN_BLK + t * 4;
  int d[4];
  int s = 0;
#pragma unroll
  for (int q = 0; q < 4; ++q) {
    int i = base + q;
    d[q] = (i < n) ? deg[i] : 0;
    s += d[q];
  }
  lds[t] = s;
  __syncthreads();
  for (int o = 1; o < 256; o <<= 1) {
    int v = (t >= o) ? lds[t - o] : 0;
    __syncthreads();
    lds[t] += v;
    __syncthreads();
  }
  int excl = lds[t] - s + bsum[blockIdx.x];
#pragma unroll
  for (int q = 0; q < 4; ++q) {
    int i = base + q;
    if (i < n) {
      off[i] = excl;
      cur[i] = excl;
    }
    excl += d[q];
  }
}

// ---------- CSR build: fill packed edge array ----------
__global__ __launch_bounds__(256)
void fill_kernel(const int* __restrict__ src, const int* __restrict__ dst,
                 const int* __restrict__ et, int* __restrict__ cur,
                 int* __restrict__ epk, int nEdges) {
  for (int e = blockIdx.x * 256 + threadIdx.x; e < nEdges; e += gridDim.x * 256) {
    int d = dst[e];
    int pos = atomicAdd(&cur[d], 1);
    epk[pos] = src[e] | (et[e] << 17);
  }
}

// ---------- gather-mean (R5-proven form) ; optional tail: zero DEG for next layer ----------
__global__ __launch_bounds__(256)
void gather_mean_kernel(const int* __restrict__ off, const int* __restrict__ epk,
                        const ushort* __restrict__ H, const float* __restrict__ REL,
                        float* __restrict__ MEAN, int doBN, float* __restrict__ acc,
                        int* __restrict__ degZero, int nNodes) {
  const uint2* H2 = (const uint2*)H;
  const float4* R4 = (const float4*)REL;
  float4* M4 = (float4*)MEAN;
  int t = threadIdx.x;
  int j = t & 31;
  int slot = t >> 5;
  float4 s1 = {0.f, 0.f, 0.f, 0.f}, s2 = {0.f, 0.f, 0.f, 0.f};
  for (int n = blockIdx.x * 8 + slot; n < nNodes; n += gridDim.x * 8) {
    int beg = off[n], end = off[n + 1];
    float4 a = {0.f, 0.f, 0.f, 0.f};
    int p = beg;
#pragma unroll 1
    for (; p + 4 <= end; p += 4) {
      int u0 = epk[p + 0];
      int u1 = epk[p + 1];
      int u2 = epk[p + 2];
      int u3 = epk[p + 3];
      uint2 h0 = H2[(size_t)(u0 & 0x1FFFF) * 32 + j];
      uint2 h1 = H2[(size_t)(u1 & 0x1FFFF) * 32 + j];
      uint2 h2 = H2[(size_t)(u2 & 0x1FFFF) * 32 + j];
      uint2 h3 = H2[(size_t)(u3 & 0x1FFFF) * 32 + j];
      float4 r0 = R4[(u0 >> 17) * 32 + j];
      float4 r1 = R4[(u1 >> 17) * 32 + j];
      float4 r2 = R4[(u2 >> 17) * 32 + j];
      float4 r3 = R4[(u3 >> 17) * 32 + j];
      a.x += (bf_lo(h0.x) + r0.x) + (bf_lo(h1.x) + r1.x) +
             (bf_lo(h2.x) + r2.x) + (bf_lo(h3.x) + r3.x);
      a.y += (bf_hi(h0.x) + r0.y) + (bf_hi(h1.x) + r1.y) +
             (bf_hi(h2.x) + r2.y) + (bf_hi(h3.x) + r3.y);
      a.z += (bf_lo(h0.y) + r0.z) + (bf_lo(h1.y) + r1.z) +
             (bf_lo(h2.y) + r2.z) + (bf_lo(h3.y) + r3.z);
      a.w += (bf_hi(h0.y) + r0.w) + (bf_hi(h1.y) + r1.w) +
             (bf_hi(h2.y) + r2.w) + (bf_hi(h3.y) + r3.w);
    }
#pragma unroll 1
    for (; p < end; ++p) {
      int u = epk[p];
      uint2 hv = H2[(size_t)(u & 0x1FFFF) * 32 + j];
      float4 rv = R4[(u >> 17) * 32 + j];
      a.x += bf_lo(hv.x) + rv.x; a.y += bf_hi(hv.x) + rv.y;
      a.z += bf_lo(hv.y) + rv.z; a.w += bf_hi(hv.y) + rv.w;
    }
    float rd = (end > beg) ? 1.f / (float)(end - beg) : 0.f;
    a.x *= rd; a.y *= rd; a.z *= rd; a.w *= rd;
    M4[(size_t)n * 32 + j] = a;
    if (doBN) {
      s1.x += a.x; s1.y += a.y; s1.z += a.z; s1.w += a.w;
      s2.x += a.x * a.x; s2.y += a.y * a.y;
      s2.z += a.z * a.z; s2.w += a.w * a.w;
    }
  }
  if (degZero) {
    for (int g = blockIdx.x * 256 + t; g < N_NODES; g += gridDim.x * 256)
      degZero[g] = 0;
  }
  if (doBN) {
    __shared__ float4 r1[8][32], r2[8][32];
    r1[slot][j] = s1;
    r2[slot][j] = s2;
    __syncthreads();
    if (slot == 0) {
      float4 a1 = r1[0][j], a2 = r2[0][j];
#pragma unroll
      for (int k = 1; k < 8; ++k) {
        float4 b1 = r1[k][j], b2 = r2[k][j];
        a1.x += b1.x; a1.y += b1.y; a1.z += b1.z; a1.w += b1.w;
        a2.x += b2.x; a2.y += b2.y; a2.z += b2.z; a2.w += b2.w;
      }
      atomicAdd(&acc[4 * j + 0], a1.x);
      atomicAdd(&acc[4 * j + 1], a1.y);
      atomicAdd(&acc[4 * j + 2], a1.z);
      atomicAdd(&acc[4 * j + 3], a1.w);
      atomicAdd(&acc[FEAT_D + 4 * j + 0], a2.x);
      atomicAdd(&acc[FEAT_D + 4 * j + 1], a2.y);
      atomicAdd(&acc[FEAT_D + 4 * j + 2], a2.z);
      atomicAdd(&acc[FEAT_D + 4 * j + 3], a2.w);
    }
  }
}

// ---------- H1 = relu(MEAN @ aggre_W + b) -> bf16 ; tail: histogram of layer-1 dst ----------
__global__ __launch_bounds__(256)
void h1_kernel(const float* __restrict__ mean, const float* __restrict__ W,
               const float* __restrict__ bias, ushort* __restrict__ H,
               const int* __restrict__ dst1, int* __restrict__ deg, int nNodes) {
  __shared__ float WT[FEAT_D * FEAT_D];
  __shared__ float bs[FEAT_D];
  int t = threadIdx.x;
  for (int i = t; i < FEAT_D * FEAT_D; i += 256) {
    int k = i >> 7, j = i & 127;
    WT[j * FEAT_D + k] = W[i];
  }
  if (t < FEAT_D) bs[t] = bias[t];
  __syncthreads();
  for (int n = blockIdx.x * 256 + t; n < nNodes; n += gridDim.x * 256) {
    float x[FEAT_D];
    const float4* xp = (const float4*)(mean + (size_t)n * FEAT_D);
#pragma unroll
    for (int q = 0; q < 32; ++q) {
      float4 v = xp[q];
      x[4 * q + 0] = v.x; x[4 * q + 1] = v.y;
      x[4 * q + 2] = v.z; x[4 * q + 3] = v.w;
    }
    uint2* orow = (uint2*)(H + (size_t)n * FEAT_D);
    for (int j4 = 0; j4 < 32; ++j4) {
      float4 a;
      a.x = bs[4 * j4 + 0]; a.y = bs[4 * j4 + 1];
      a.z = bs[4 * j4 + 2]; a.w = bs[4 * j4 + 3];
      const float4* w0 = (const float4*)&WT[(4 * j4 + 0) * FEAT_D];
      const float4* w1 = (const float4*)&WT[(4 * j4 + 1) * FEAT_D];
      const float4* w2 = (const float4*)&WT[(4 * j4 + 2) * FEAT_D];
      const float4* w3 = (const float4*)&WT[(4 * j4 + 3) * FEAT_D];
#pragma unroll
      for (int q = 0; q < 32; ++q) {
        float4 v0 = w0[q], v1 = w1[q], v2 = w2[q], v3 = w3[q];
        a.x = fmaf(x[4*q+0], v0.x, a.x); a.x = fmaf(x[4*q+1], v0.y, a.x);
        a.x = fmaf(x[4*q+2], v0.z, a.x); a.x = fmaf(x[4*q+3], v0.w, a.x);
        a.y = fmaf(x[4*q+0], v1.x, a.y); a.y = fmaf(x[4*q+1], v1.y, a.y);
        a.y = fmaf(x[4*q+2], v1.z, a.y); a.y = fmaf(x[4*q+3], v1.w, a.y);
        a.z = fmaf(x[4*q+0], v2.x, a.z); a.z = fmaf(x[4*q+1], v2.y, a.z);
        a.z = fmaf(x[4*q+2], v2.z, a.z); a.z = fmaf(x[4*q+3], v2.w, a.z);
        a.w = fmaf(x[4*q+0], v3.x, a.w); a.w = fmaf(x[4*q+1], v3.y, a.w);
        a.w = fmaf(x[4*q+2], v3.z, a.w); a.w = fmaf(x[4*q+3], v3.w, a.w);
      }
      a.x = fmaxf(a.x, 0.f); a.y = fmaxf(a.y, 0.f);
      a.z = fmaxf(a.z, 0.f); a.w = fmaxf(a.w, 0.f);
      uint2 pk; pk.x = packbf2(a.x, a.y); pk.y = packbf2(a.z, a.w);
      orow[j4] = pk;
    }
  }
  // tail: layer-1 dst histogram (DEG zeroed by gather-0's tail)
  for (int e = blockIdx.x * 256 + t; e < N_EDGES; e += gridDim.x * 256)
    atomicAdd(&deg[dst1[e]], 1);
}

// ---------- final: one node per WAVE, x in LDS, padded weight columns ----------
#define W0_LDX 129   // odd stride: bank = (lane + k) & 31, conflict-free
#define W2_LDX 33
__global__ __launch_bounds__(256)
void final_kernel(const float* __restrict__ mean, const float* __restrict__ acc,
                  const float* __restrict__ gamma, const float* __restrict__ beta,
                  const float* __restrict__ fc0w, const float* __restrict__ fc0b,
                  const float* __restrict__ fc1w, const float* __restrict__ fc1b,
                  const float* __restrict__ fc2w, const float* __restrict__ fc2b,
                  float* __restrict__ out, int nNodes) {
  __shared__ float W0T[64 * W0_LDX];     // 33,024 B  W0T[j*129+k] = fc0w[k*64+j]
  __shared__ float W1L[64 * 32];         //  8,192 B  fc1w as-is
  __shared__ float W2T[N_CLS * W2_LDX];  //  6,600 B  W2T[c*33+jj] = fc2w[jj*50+c]
  __shared__ float sc[FEAT_D], sh[FEAT_D];
  __shared__ float b0[64], b1[32], b2s[N_CLS];
  __shared__ float xs[4][FEAT_D];        // per-wave node row
  __shared__ float h1s[4][64], h2s[4][32];
  int t = threadIdx.x;
  for (int i = t; i < 64 * FEAT_D; i += 256) {
    int k = i >> 6, j = i & 63;
    W0T[j * W0_LDX + k] = fc0w[i];
  }
  for (int i = t; i < 64 * 32; i += 256) W1L[i] = fc1w[i];
  for (int i = t; i < 32 * N_CLS; i += 256) {
    int jj = i / N_CLS, c = i % N_CLS;
    W2T[c * W2_LDX + jj] = fc2w[i];
  }
  if (t < FEAT_D) {
    float m = acc[t] * (1.f / (float)N_NODES);
    float v = acc[FEAT_D + t] * (1.f / (float)N_NODES) - m * m;
    float r = rsqrtf(v + BN_EPS);
    float g = gamma[t];
    sc[t] = r * g;
    sh[t] = beta[t] - m * r * g;
  }
  if (t < 64) b0[t] = fc0b[t];
  if (t < 32) b1[t] = fc1b[t];
  if (t < N_CLS) b2s[t] = fc2b[t];
  __syncthreads();
  int w = t >> 6, lane = t & 63;
  for (int base = blockIdx.x * 4; base < nNodes; base += gridDim.x * 4) {
    int n = base + w;
    bool ok = (n < nNodes);
    if (ok) {
      float2 v = *(const float2*)(mean + (size_t)n * FEAT_D + 2 * lane);
      xs[w][2 * lane + 0] = fmaxf(fmaf(v.x, sc[2 * lane + 0], sh[2 * lane + 0]), 0.f);
      xs[w][2 * lane + 1] = fmaxf(fmaf(v.y, sc[2 * lane + 1], sh[2 * lane + 1]), 0.f);
    }
    __syncthreads();
    if (ok) {  // fc0: lane j computes h1[j], all 64 lanes active
      const float* wr = &W0T[lane * W0_LDX];
      float a0 = b0[lane], a1 = 0.f, a2 = 0.f, a3 = 0.f;
#pragma unroll
      for (int k = 0; k < FEAT_D; k += 4) {
        float4 xv = *(const float4*)&xs[w][k];
        a0 = fmaf(xv.x, wr[k + 0], a0);
        a1 = fmaf(xv.y, wr[k + 1], a1);
        a2 = fmaf(xv.z, wr[k + 2], a2);
        a3 = fmaf(xv.w, wr[k + 3], a3);
      }
      h1s[w][lane] = fmaxf((a0 + a1) + (a2 + a3), 0.f);
    }
    __syncthreads();
    if (ok && lane < 32) {  // fc1
      float a0 = b1[lane], a1 = 0.f;
#pragma unroll
      for (int j = 0; j < 64; j += 2) {
        a0 = fmaf(h1s[w][j + 0], W1L[(j + 0) * 32 + lane], a0);
        a1 = fmaf(h1s[w][j + 1], W1L[(j + 1) * 32 + lane], a1);
      }
      h2s[w][lane] = fmaxf(a0 + a1, 0.f);
    }
    __syncthreads();
    if (ok && lane < N_CLS) {  // fc2
      const float* wr = &W2T[lane * W2_LDX];
      float a0 = b2s[lane], a1 = 0.f;
#pragma unroll
      for (int jj = 0; jj < 32; jj += 2) {
        a0 = fmaf(h2s[w][jj + 0], wr[jj + 0], a0);
        a1 = fmaf(h2s[w][jj + 1], wr[jj + 1], a1);
      }
      out[(size_t)n * N_CLS + lane] = a0 + a1;
    }
    __syncthreads();
  }
}

extern "C" void kernel_launch(void* const* d_in, const int* in_sizes, int n_in,
                              void* d_out, int out_size, void* d_ws, size_t ws_size,
                              hipStream_t stream) {
  const int* edge_src = (const int*)d_in[0];
  const int* edge_dst = (const int*)d_in[1];
  const int* edge_type = (const int*)d_in[2];
  const float* emb_h = (const float*)d_in[3];
  const float* emb_e = (const float*)d_in[4];
  const float* rel_wt = (const float*)d_in[5];
  const float* W_h_init = (const float*)d_in[6];
  const float* W_e_init = (const float*)d_in[7];
  const float* aggre_W = (const float*)d_in[8];
  const float* aggre_b = (const float*)d_in[9];
  const float* bn_gamma = (const float*)d_in[10];
  const float* bn_beta = (const float*)d_in[11];
  const float* fc0_w = (const float*)d_in[12];
  const float* fc0_b = (const float*)d_in[13];
  const float* fc1_w = (const float*)d_in[14];
  const float* fc1_b = (const float*)d_in[15];
  const float* fc2_w = (const float*)d_in[16];
  const float* fc2_b = (const float*)d_in[17];
  float* out = (float*)d_out;

  // ---- workspace layout (bytes): ~77 MB ----
  char* ws = (char*)d_ws;
  float*  REL  = (float*)(ws);                    // 102,400
  float*  WC   = (float*)(ws + 102400);           // 51,200
  ushort* H    = (ushort*)(ws + 153600);          // 25,600,000
  float*  MEAN = (float*)(ws + 25753600);         // 51,200,000
  float*  ACC  = (float*)(ws + 76953600);         // 1,024

  // ---- CSR scratch lives in d_out (20 MB); final_kernel overwrites it last ----
  char* ob = (char*)d_out;
  int* EPK  = (int*)(ob);                        // 2,000,000
  int* DEG  = (int*)(ob + 2000000);              // 400,000
  int* OFF  = (int*)(ob + 2400000);              // 400,004
  int* CUR  = (int*)(ob + 2800004);              // 400,004
  int* BSUM = (int*)(ob + 3200008);              // 392

  const int NODE_BLOCKS = (N_NODES + 255) / 256;  // 391
  const int GATHER_BLOCKS = 2048;

  // relwc also zeroes DEG (for layer-0 hist) and ACC
  relwc_kernel<<<N_RELS + INIT_D, 128, 0, stream>>>(rel_wt, emb_e, W_e_init, REL,
                                                    W_h_init, aggre_W, WC, DEG, ACC);
  // h0 also runs the layer-0 dst histogram in its tail
  h0_kernel<<<NODE_BLOCKS, 256, 0, stream>>>(emb_h, WC, aggre_b, H, edge_dst, DEG,
                                             N_NODES);

  // ---- layer 0: scans + fill + gather (gather tail re-zeroes DEG for layer 1) ----
  scanA_kernel<<<NB_SCAN, 256, 0, stream>>>(DEG, BSUM, N_NODES);
  scanBw_kernel<<<1, 128, 0, stream>>>(BSUM, NB_SCAN, OFF);
  scanC_kernel<<<NB_SCAN, 256, 0, stream>>>(DEG, BSUM, OFF, CUR, N_NODES);
  fill_kernel<<<1024, 256, 0, stream>>>(edge_src, edge_dst, edge_type, CUR, EPK,
                                        N_EDGES);
  gather_mean_kernel<<<GATHER_BLOCKS, 256, 0, stream>>>(OFF, EPK, H, REL, MEAN, 0,
                                                        ACC, DEG, N_NODES);

  // h1 also runs the layer-1 dst histogram in its tail
  h1_kernel<<<NODE_BLOCKS, 256, 0, stream>>>(MEAN, aggre_W, aggre_b, H,
                                             edge_dst + N_EDGES, DEG, N_NODES);

  // ---- layer 1: scans + fill + gather (+BN stats) ----
  scanA_kernel<<<NB_SCAN, 256, 0, stream>>>(DEG, BSUM, N_NODES);
  scanBw_kernel<<<1, 128, 0, stream>>>(BSUM, NB_SCAN, OFF);
  scanC_kernel<<<NB_SCAN, 256, 0, stream>>>(DEG, BSUM, OFF, CUR, N_NODES);
  fill_kernel<<<1024, 256, 0, stream>>>(edge_src + N_EDGES, edge_dst + N_EDGES,
                                        edge_type + N_EDGES, CUR, EPK, N_EDGES);
  gather_mean_kernel<<<GATHER_BLOCKS, 256, 0, stream>>>(OFF, EPK, H, REL, MEAN, 1,
                                                        ACC, nullptr, N_NODES);

  final_kernel<<<2048, 256, 0, stream>>>(MEAN, ACC, bn_gamma, bn_beta,
                                         fc0_w, fc0_b, fc1_w, fc1_b,
                                         fc2_w, fc2_b, out, N_NODES);
}

// Round 11
// 639.570 us; speedup vs baseline: 1.6102x; 1.0133x over previous
//
#include <hip/hip_runtime.h>
#include <cstdint>
#include <cstddef>

#define N_NODES 100000
#define N_EDGES 500000
#define N_RELS  200
#define N_BASE  50
#define INIT_D  100
#define FEAT_D  128
#define N_CLS   50
#define BN_EPS  1e-5f

#define SCAN_BLK 1024
#define NB_SCAN  ((N_NODES + SCAN_BLK - 1) / SCAN_BLK)   // 98

typedef unsigned int uint;
typedef unsigned short ushort;

// bf16 helpers (RNE pack, cheap unpack)
__device__ inline uint packbf2(float a, float b) {
  uint ua = __float_as_uint(a); ua = (ua + 0x7fffu + ((ua >> 16) & 1u)) >> 16;
  uint ub = __float_as_uint(b); ub = (ub + 0x7fffu + ((ub >> 16) & 1u)) >> 16;
  return ua | (ub << 16);
}
__device__ inline float bf_lo(uint u) { return __uint_as_float(u << 16); }
__device__ inline float bf_hi(uint u) { return __uint_as_float(u & 0xffff0000u); }

// ---------- fused: REL rows (blocks 0..199), WC rows (200..299); zeroes DEG+ACC ----------
__global__ __launch_bounds__(128)
void relwc_kernel(const float* __restrict__ rel_wt, const float* __restrict__ emb_e,
                  const float* __restrict__ W_e, float* __restrict__ REL,
                  const float* __restrict__ W_h, const float* __restrict__ aggre_W,
                  float* __restrict__ WC, int* __restrict__ deg,
                  float* __restrict__ acc) {
  __shared__ float T[FEAT_D];
  int t = threadIdx.x;
  for (int g = blockIdx.x * 128 + t; g < N_NODES; g += gridDim.x * 128) deg[g] = 0;
  if (blockIdx.x == 0) {
    for (int g = t; g < 2 * FEAT_D; g += 128) acc[g] = 0.f;
  }
  if (blockIdx.x < N_RELS) {
    int r = blockIdx.x;
    if (t < INIT_D) {
      float a = 0.f;
      for (int b = 0; b < N_BASE; ++b)
        a += rel_wt[r * N_BASE + b] * emb_e[b * INIT_D + t];
      T[t] = a;
    }
    __syncthreads();
    float a = 0.f;
    for (int k = 0; k < INIT_D; ++k)
      a += T[k] * W_e[k * FEAT_D + t];
    REL[r * FEAT_D + t] = a;
  } else {
    int i = blockIdx.x - N_RELS;
    T[t] = W_h[i * FEAT_D + t];
    __syncthreads();
    float a = 0.f;
    for (int f = 0; f < FEAT_D; ++f)
      a += T[f] * aggre_W[f * FEAT_D + t];
    WC[i * FEAT_D + t] = a;
  }
}

// ---------- H0 = relu(emb_h @ WC + b) -> bf16 ; tail: histogram of layer-0 dst ----------
__global__ __launch_bounds__(256)
void h0_kernel(const float* __restrict__ emb_h, const float* __restrict__ WC,
               const float* __restrict__ bias, ushort* __restrict__ H,
               const int* __restrict__ dst0, int* __restrict__ deg, int nNodes) {
  __shared__ float WT[FEAT_D * INIT_D];
  __shared__ float bs[FEAT_D];
  int t = threadIdx.x;
  for (int i = t; i < FEAT_D * INIT_D; i += 256) {
    int k = i >> 7, j = i & 127;
    WT[j * INIT_D + k] = WC[i];
  }
  if (t < FEAT_D) bs[t] = bias[t];
  __syncthreads();
  for (int n = blockIdx.x * 256 + t; n < nNodes; n += gridDim.x * 256) {
    float x[INIT_D];
    const float4* xp = (const float4*)(emb_h + (size_t)n * INIT_D);
#pragma unroll
    for (int q = 0; q < 25; ++q) {
      float4 v = xp[q];
      x[4 * q + 0] = v.x; x[4 * q + 1] = v.y; x[4 * q + 2] = v.z; x[4 * q + 3] = v.w;
    }
    uint2* orow = (uint2*)(H + (size_t)n * FEAT_D);
    for (int j4 = 0; j4 < 32; ++j4) {
      float4 a;
      a.x = bs[4 * j4 + 0]; a.y = bs[4 * j4 + 1];
      a.z = bs[4 * j4 + 2]; a.w = bs[4 * j4 + 3];
      const float4* w0 = (const float4*)&WT[(4 * j4 + 0) * INIT_D];
      const float4* w1 = (const float4*)&WT[(4 * j4 + 1) * INIT_D];
      const float4* w2 = (const float4*)&WT[(4 * j4 + 2) * INIT_D];
      const float4* w3 = (const float4*)&WT[(4 * j4 + 3) * INIT_D];
#pragma unroll
      for (int q = 0; q < 25; ++q) {
        float4 v0 = w0[q], v1 = w1[q], v2 = w2[q], v3 = w3[q];
        a.x = fmaf(x[4*q+0], v0.x, a.x); a.x = fmaf(x[4*q+1], v0.y, a.x);
        a.x = fmaf(x[4*q+2], v0.z, a.x); a.x = fmaf(x[4*q+3], v0.w, a.x);
        a.y = fmaf(x[4*q+0], v1.x, a.y); a.y = fmaf(x[4*q+1], v1.y, a.y);
        a.y = fmaf(x[4*q+2], v1.z, a.y); a.y = fmaf(x[4*q+3], v1.w, a.y);
        a.z = fmaf(x[4*q+0], v2.x, a.z); a.z = fmaf(x[4*q+1], v2.y, a.z);
        a.z = fmaf(x[4*q+2], v2.z, a.z); a.z = fmaf(x[4*q+3], v2.w, a.z);
        a.w = fmaf(x[4*q+0], v3.x, a.w); a.w = fmaf(x[4*q+1], v3.y, a.w);
        a.w = fmaf(x[4*q+2], v3.z, a.w); a.w = fmaf(x[4*q+3], v3.w, a.w);
      }
      a.x = fmaxf(a.x, 0.f); a.y = fmaxf(a.y, 0.f);
      a.z = fmaxf(a.z, 0.f); a.w = fmaxf(a.w, 0.f);
      uint2 pk; pk.x = packbf2(a.x, a.y); pk.y = packbf2(a.z, a.w);
      orow[j4] = pk;
    }
  }
  for (int e = blockIdx.x * 256 + t; e < N_EDGES; e += gridDim.x * 256)
    atomicAdd(&deg[dst0[e]], 1);
}

// ---------- CSR build: per-block sums of deg ----------
__global__ __launch_bounds__(256)
void scanA_kernel(const int* __restrict__ deg, int* __restrict__ bsum, int n) {
  __shared__ int red[256];
  int t = threadIdx.x;
  int base = blockIdx.x * SCAN_BLK + t * 4;
  int s = 0;
#pragma unroll
  for (int q = 0; q < 4; ++q) {
    int i = base + q;
    s += (i < n) ? deg[i] : 0;
  }
  red[t] = s;
  __syncthreads();
  for (int off = 128; off > 0; off >>= 1) {
    if (t < off) red[t] += red[t + off];
    __syncthreads();
  }
  if (t == 0) bsum[blockIdx.x] = red[0];
}

// ---------- CSR build: wave-parallel scan of the 98 block sums ----------
__global__ __launch_bounds__(128)
void scanBw_kernel(int* __restrict__ bsum, int nb, int* __restrict__ off) {
  __shared__ int s[128];
  int t = threadIdx.x;
  int v = (t < nb) ? bsum[t] : 0;
  s[t] = v;
  __syncthreads();
  for (int o = 1; o < 128; o <<= 1) {
    int u = (t >= o) ? s[t - o] : 0;
    __syncthreads();
    s[t] += u;
    __syncthreads();
  }
  if (t < nb) bsum[t] = s[t] - v;
  if (t == nb - 1) off[N_NODES] = s[t];
}

// ---------- CSR build: final offsets (exclusive scan) + cursor copy ----------
__global__ __launch_bounds__(256)
void scanC_kernel(const int* __restrict__ deg, const int* __restrict__ bsum,
                  int* __restrict__ off, int* __restrict__ cur, int n) {
  __shared__ int lds[256];
  int t = threadIdx.x;
  int base = blockIdx.x * SCAN_BLK + t * 4;
  int d[4];
  int s = 0;
#pragma unroll
  for (int q = 0; q < 4; ++q) {
    int i = base + q;
    d[q] = (i < n) ? deg[i] : 0;
    s += d[q];
  }
  lds[t] = s;
  __syncthreads();
  for (int o = 1; o < 256; o <<= 1) {
    int v = (t >= o) ? lds[t - o] : 0;
    __syncthreads();
    lds[t] += v;
    __syncthreads();
  }
  int excl = lds[t] - s + bsum[blockIdx.x];
#pragma unroll
  for (int q = 0; q < 4; ++q) {
    int i = base + q;
    if (i < n) {
      off[i] = excl;
      cur[i] = excl;
    }
    excl += d[q];
  }
}

// ---------- CSR build: fill packed edge array ----------
__global__ __launch_bounds__(256)
void fill_kernel(const int* __restrict__ src, const int* __restrict__ dst,
                 const int* __restrict__ et, int* __restrict__ cur,
                 int* __restrict__ epk, int nEdges) {
  for (int e = blockIdx.x * 256 + threadIdx.x; e < nEdges; e += gridDim.x * 256) {
    int d = dst[e];
    int pos = atomicAdd(&cur[d], 1);
    epk[pos] = src[e] | (et[e] << 17);
  }
}

// ---------- gather-mean: bf16 H rows in, packed-bf16 MEAN out; fp32 BN stats ----------
__global__ __launch_bounds__(256)
void gather_mean_kernel(const int* __restrict__ off, const int* __restrict__ epk,
                        const ushort* __restrict__ H, const float* __restrict__ REL,
                        ushort* __restrict__ MEANB, int doBN, float* __restrict__ acc,
                        int* __restrict__ degZero, int nNodes) {
  const uint2* H2 = (const uint2*)H;
  const float4* R4 = (const float4*)REL;
  uint2* MB2 = (uint2*)MEANB;   // 32 uint2 per 128-feat bf16 row
  int t = threadIdx.x;
  int j = t & 31;
  int slot = t >> 5;
  float4 s1 = {0.f, 0.f, 0.f, 0.f}, s2 = {0.f, 0.f, 0.f, 0.f};
  for (int n = blockIdx.x * 8 + slot; n < nNodes; n += gridDim.x * 8) {
    int beg = off[n], end = off[n + 1];
    float4 a = {0.f, 0.f, 0.f, 0.f};
    int p = beg;
#pragma unroll 1
    for (; p + 4 <= end; p += 4) {
      int u0 = epk[p + 0];
      int u1 = epk[p + 1];
      int u2 = epk[p + 2];
      int u3 = epk[p + 3];
      uint2 h0 = H2[(size_t)(u0 & 0x1FFFF) * 32 + j];
      uint2 h1 = H2[(size_t)(u1 & 0x1FFFF) * 32 + j];
      uint2 h2 = H2[(size_t)(u2 & 0x1FFFF) * 32 + j];
      uint2 h3 = H2[(size_t)(u3 & 0x1FFFF) * 32 + j];
      float4 r0 = R4[(u0 >> 17) * 32 + j];
      float4 r1 = R4[(u1 >> 17) * 32 + j];
      float4 r2 = R4[(u2 >> 17) * 32 + j];
      float4 r3 = R4[(u3 >> 17) * 32 + j];
      a.x += (bf_lo(h0.x) + r0.x) + (bf_lo(h1.x) + r1.x) +
             (bf_lo(h2.x) + r2.x) + (bf_lo(h3.x) + r3.x);
      a.y += (bf_hi(h0.x) + r0.y) + (bf_hi(h1.x) + r1.y) +
             (bf_hi(h2.x) + r2.y) + (bf_hi(h3.x) + r3.y);
      a.z += (bf_lo(h0.y) + r0.z) + (bf_lo(h1.y) + r1.z) +
             (bf_lo(h2.y) + r2.z) + (bf_lo(h3.y) + r3.z);
      a.w += (bf_hi(h0.y) + r0.w) + (bf_hi(h1.y) + r1.w) +
             (bf_hi(h2.y) + r2.w) + (bf_hi(h3.y) + r3.w);
    }
#pragma unroll 1
    for (; p < end; ++p) {
      int u = epk[p];
      uint2 hv = H2[(size_t)(u & 0x1FFFF) * 32 + j];
      float4 rv = R4[(u >> 17) * 32 + j];
      a.x += bf_lo(hv.x) + rv.x; a.y += bf_hi(hv.x) + rv.y;
      a.z += bf_lo(hv.y) + rv.z; a.w += bf_hi(hv.y) + rv.w;
    }
    float rd = (end > beg) ? 1.f / (float)(end - beg) : 0.f;
    a.x *= rd; a.y *= rd; a.z *= rd; a.w *= rd;
    uint2 pk; pk.x = packbf2(a.x, a.y); pk.y = packbf2(a.z, a.w);
    MB2[(size_t)n * 32 + j] = pk;
    if (doBN) {  // stats from pre-pack fp32 values
      s1.x += a.x; s1.y += a.y; s1.z += a.z; s1.w += a.w;
      s2.x += a.x * a.x; s2.y += a.y * a.y;
      s2.z += a.z * a.z; s2.w += a.w * a.w;
    }
  }
  if (degZero) {
    for (int g = blockIdx.x * 256 + t; g < N_NODES; g += gridDim.x * 256)
      degZero[g] = 0;
  }
  if (doBN) {
    __shared__ float4 r1[8][32], r2[8][32];
    r1[slot][j] = s1;
    r2[slot][j] = s2;
    __syncthreads();
    if (slot == 0) {
      float4 a1 = r1[0][j], a2 = r2[0][j];
#pragma unroll
      for (int k = 1; k < 8; ++k) {
        float4 b1 = r1[k][j], b2 = r2[k][j];
        a1.x += b1.x; a1.y += b1.y; a1.z += b1.z; a1.w += b1.w;
        a2.x += b2.x; a2.y += b2.y; a2.z += b2.z; a2.w += b2.w;
      }
      atomicAdd(&acc[4 * j + 0], a1.x);
      atomicAdd(&acc[4 * j + 1], a1.y);
      atomicAdd(&acc[4 * j + 2], a1.z);
      atomicAdd(&acc[4 * j + 3], a1.w);
      atomicAdd(&acc[FEAT_D + 4 * j + 0], a2.x);
      atomicAdd(&acc[FEAT_D + 4 * j + 1], a2.y);
      atomicAdd(&acc[FEAT_D + 4 * j + 2], a2.z);
      atomicAdd(&acc[FEAT_D + 4 * j + 3], a2.w);
    }
  }
}

// ---------- H1 = relu(MEANB(bf16) @ aggre_W + b) -> bf16 ; tail: layer-1 histogram ----------
__global__ __launch_bounds__(256)
void h1_kernel(const ushort* __restrict__ meanb, const float* __restrict__ W,
               const float* __restrict__ bias, ushort* __restrict__ H,
               const int* __restrict__ dst1, int* __restrict__ deg, int nNodes) {
  __shared__ float WT[FEAT_D * FEAT_D];
  __shared__ float bs[FEAT_D];
  int t = threadIdx.x;
  for (int i = t; i < FEAT_D * FEAT_D; i += 256) {
    int k = i >> 7, j = i & 127;
    WT[j * FEAT_D + k] = W[i];
  }
  if (t < FEAT_D) bs[t] = bias[t];
  __syncthreads();
  for (int n = blockIdx.x * 256 + t; n < nNodes; n += gridDim.x * 256) {
    float x[FEAT_D];
    const uint4* xp = (const uint4*)(meanb + (size_t)n * FEAT_D);  // 16 uint4/row
#pragma unroll
    for (int q = 0; q < 16; ++q) {
      uint4 v = xp[q];
      x[8*q+0] = bf_lo(v.x); x[8*q+1] = bf_hi(v.x);
      x[8*q+2] = bf_lo(v.y); x[8*q+3] = bf_hi(v.y);
      x[8*q+4] = bf_lo(v.z); x[8*q+5] = bf_hi(v.z);
      x[8*q+6] = bf_lo(v.w); x[8*q+7] = bf_hi(v.w);
    }
    uint2* orow = (uint2*)(H + (size_t)n * FEAT_D);
    for (int j4 = 0; j4 < 32; ++j4) {
      float4 a;
      a.x = bs[4 * j4 + 0]; a.y = bs[4 * j4 + 1];
      a.z = bs[4 * j4 + 2]; a.w = bs[4 * j4 + 3];
      const float4* w0 = (const float4*)&WT[(4 * j4 + 0) * FEAT_D];
      const float4* w1 = (const float4*)&WT[(4 * j4 + 1) * FEAT_D];
      const float4* w2 = (const float4*)&WT[(4 * j4 + 2) * FEAT_D];
      const float4* w3 = (const float4*)&WT[(4 * j4 + 3) * FEAT_D];
#pragma unroll
      for (int q = 0; q < 32; ++q) {
        float4 v0 = w0[q], v1 = w1[q], v2 = w2[q], v3 = w3[q];
        a.x = fmaf(x[4*q+0], v0.x, a.x); a.x = fmaf(x[4*q+1], v0.y, a.x);
        a.x = fmaf(x[4*q+2], v0.z, a.x); a.x = fmaf(x[4*q+3], v0.w, a.x);
        a.y = fmaf(x[4*q+0], v1.x, a.y); a.y = fmaf(x[4*q+1], v1.y, a.y);
        a.y = fmaf(x[4*q+2], v1.z, a.y); a.y = fmaf(x[4*q+3], v1.w, a.y);
        a.z = fmaf(x[4*q+0], v2.x, a.z); a.z = fmaf(x[4*q+1], v2.y, a.z);
        a.z = fmaf(x[4*q+2], v2.z, a.z); a.z = fmaf(x[4*q+3], v2.w, a.z);
        a.w = fmaf(x[4*q+0], v3.x, a.w); a.w = fmaf(x[4*q+1], v3.y, a.w);
        a.w = fmaf(x[4*q+2], v3.z, a.w); a.w = fmaf(x[4*q+3], v3.w, a.w);
      }
      a.x = fmaxf(a.x, 0.f); a.y = fmaxf(a.y, 0.f);
      a.z = fmaxf(a.z, 0.f); a.w = fmaxf(a.w, 0.f);
      uint2 pk; pk.x = packbf2(a.x, a.y); pk.y = packbf2(a.z, a.w);
      orow[j4] = pk;
    }
  }
  for (int e = blockIdx.x * 256 + t; e < N_EDGES; e += gridDim.x * 256)
    atomicAdd(&deg[dst1[e]], 1);
}

// ---------- final: one node per WAVE, x in LDS, padded weight columns ----------
#define W0_LDX 129   // odd stride: bank = (lane + k) & 31, conflict-free
#define W2_LDX 33
__global__ __launch_bounds__(256)
void final_kernel(const ushort* __restrict__ meanb, const float* __restrict__ acc,
                  const float* __restrict__ gamma, const float* __restrict__ beta,
                  const float* __restrict__ fc0w, const float* __restrict__ fc0b,
                  const float* __restrict__ fc1w, const float* __restrict__ fc1b,
                  const float* __restrict__ fc2w, const float* __restrict__ fc2b,
                  float* __restrict__ out, int nNodes) {
  __shared__ float W0T[64 * W0_LDX];
  __shared__ float W1L[64 * 32];
  __shared__ float W2T[N_CLS * W2_LDX];
  __shared__ float sc[FEAT_D], sh[FEAT_D];
  __shared__ float b0[64], b1[32], b2s[N_CLS];
  __shared__ float xs[4][FEAT_D];
  __shared__ float h1s[4][64], h2s[4][32];
  int t = threadIdx.x;
  for (int i = t; i < 64 * FEAT_D; i += 256) {
    int k = i >> 6, j = i & 63;
    W0T[j * W0_LDX + k] = fc0w[i];
  }
  for (int i = t; i < 64 * 32; i += 256) W1L[i] = fc1w[i];
  for (int i = t; i < 32 * N_CLS; i += 256) {
    int jj = i / N_CLS, c = i % N_CLS;
    W2T[c * W2_LDX + jj] = fc2w[i];
  }
  if (t < FEAT_D) {
    float m = acc[t] * (1.f / (float)N_NODES);
    float v = acc[FEAT_D + t] * (1.f / (float)N_NODES) - m * m;
    float r = rsqrtf(v + BN_EPS);
    float g = gamma[t];
    sc[t] = r * g;
    sh[t] = beta[t] - m * r * g;
  }
  if (t < 64) b0[t] = fc0b[t];
  if (t < 32) b1[t] = fc1b[t];
  if (t < N_CLS) b2s[t] = fc2b[t];
  __syncthreads();
  int w = t >> 6, lane = t & 63;
  const uint* MB1 = (const uint*)meanb;  // 64 uints per row (2 bf16 each)
  for (int base = blockIdx.x * 4; base < nNodes; base += gridDim.x * 4) {
    int n = base + w;
    bool ok = (n < nNodes);
    if (ok) {
      uint v = MB1[(size_t)n * 64 + lane];
      xs[w][2 * lane + 0] = fmaxf(fmaf(bf_lo(v), sc[2 * lane + 0], sh[2 * lane + 0]), 0.f);
      xs[w][2 * lane + 1] = fmaxf(fmaf(bf_hi(v), sc[2 * lane + 1], sh[2 * lane + 1]), 0.f);
    }
    __syncthreads();
    if (ok) {
      const float* wr = &W0T[lane * W0_LDX];
      float a0 = b0[lane], a1 = 0.f, a2 = 0.f, a3 = 0.f;
#pragma unroll
      for (int k = 0; k < FEAT_D; k += 4) {
        float4 xv = *(const float4*)&xs[w][k];
        a0 = fmaf(xv.x, wr[k + 0], a0);
        a1 = fmaf(xv.y, wr[k + 1], a1);
        a2 = fmaf(xv.z, wr[k + 2], a2);
        a3 = fmaf(xv.w, wr[k + 3], a3);
      }
      h1s[w][lane] = fmaxf((a0 + a1) + (a2 + a3), 0.f);
    }
    __syncthreads();
    if (ok && lane < 32) {
      float a0 = b1[lane], a1 = 0.f;
#pragma unroll
      for (int j = 0; j < 64; j += 2) {
        a0 = fmaf(h1s[w][j + 0], W1L[(j + 0) * 32 + lane], a0);
        a1 = fmaf(h1s[w][j + 1], W1L[(j + 1) * 32 + lane], a1);
      }
      h2s[w][lane] = fmaxf(a0 + a1, 0.f);
    }
    __syncthreads();
    if (ok && lane < N_CLS) {
      const float* wr = &W2T[lane * W2_LDX];
      float a0 = b2s[lane], a1 = 0.f;
#pragma unroll
      for (int jj = 0; jj < 32; jj += 2) {
        a0 = fmaf(h2s[w][jj + 0], wr[jj + 0], a0);
        a1 = fmaf(h2s[w][jj + 1], wr[jj + 1], a1);
      }
      out[(size_t)n * N_CLS + lane] = a0 + a1;
    }
    __syncthreads();
  }
}

extern "C" void kernel_launch(void* const* d_in, const int* in_sizes, int n_in,
                              void* d_out, int out_size, void* d_ws, size_t ws_size,
                              hipStream_t stream) {
  const int* edge_src = (const int*)d_in[0];
  const int* edge_dst = (const int*)d_in[1];
  const int* edge_type = (const int*)d_in[2];
  const float* emb_h = (const float*)d_in[3];
  const float* emb_e = (const float*)d_in[4];
  const float* rel_wt = (const float*)d_in[5];
  const float* W_h_init = (const float*)d_in[6];
  const float* W_e_init = (const float*)d_in[7];
  const float* aggre_W = (const float*)d_in[8];
  const float* aggre_b = (const float*)d_in[9];
  const float* bn_gamma = (const float*)d_in[10];
  const float* bn_beta = (const float*)d_in[11];
  const float* fc0_w = (const float*)d_in[12];
  const float* fc0_b = (const float*)d_in[13];
  const float* fc1_w = (const float*)d_in[14];
  const float* fc1_b = (const float*)d_in[15];
  const float* fc2_w = (const float*)d_in[16];
  const float* fc2_b = (const float*)d_in[17];
  float* out = (float*)d_out;

  // ---- workspace layout (bytes): ~51.4 MB ----
  char* ws = (char*)d_ws;
  float*  REL   = (float*)(ws);                    // 102,400
  float*  WC    = (float*)(ws + 102400);           // 51,200
  ushort* H     = (ushort*)(ws + 153600);          // 25,600,000
  ushort* MEANB = (ushort*)(ws + 25753600);        // 25,600,000 (bf16 mean rows)
  float*  ACC   = (float*)(ws + 51353600);         // 1,024

  // ---- CSR scratch lives in d_out (20 MB); final_kernel overwrites it last ----
  char* ob = (char*)d_out;
  int* EPK  = (int*)(ob);                        // 2,000,000
  int* DEG  = (int*)(ob + 2000000);              // 400,000
  int* OFF  = (int*)(ob + 2400000);              // 400,004
  int* CUR  = (int*)(ob + 2800004);              // 400,004
  int* BSUM = (int*)(ob + 3200008);              // 392

  const int NODE_BLOCKS = (N_NODES + 255) / 256;  // 391
  const int GATHER_BLOCKS = 2048;

  relwc_kernel<<<N_RELS + INIT_D, 128, 0, stream>>>(rel_wt, emb_e, W_e_init, REL,
                                                    W_h_init, aggre_W, WC, DEG, ACC);
  h0_kernel<<<NODE_BLOCKS, 256, 0, stream>>>(emb_h, WC, aggre_b, H, edge_dst, DEG,
                                             N_NODES);

  // ---- layer 0 ----
  scanA_kernel<<<NB_SCAN, 256, 0, stream>>>(DEG, BSUM, N_NODES);
  scanBw_kernel<<<1, 128, 0, stream>>>(BSUM, NB_SCAN, OFF);
  scanC_kernel<<<NB_SCAN, 256, 0, stream>>>(DEG, BSUM, OFF, CUR, N_NODES);
  fill_kernel<<<1024, 256, 0, stream>>>(edge_src, edge_dst, edge_type, CUR, EPK,
                                        N_EDGES);
  gather_mean_kernel<<<GATHER_BLOCKS, 256, 0, stream>>>(OFF, EPK, H, REL, MEANB, 0,
                                                        ACC, DEG, N_NODES);

  h1_kernel<<<NODE_BLOCKS, 256, 0, stream>>>(MEANB, aggre_W, aggre_b, H,
                                             edge_dst + N_EDGES, DEG, N_NODES);

  // ---- layer 1 ----
  scanA_kernel<<<NB_SCAN, 256, 0, stream>>>(DEG, BSUM, N_NODES);
  scanBw_kernel<<<1, 128, 0, stream>>>(BSUM, NB_SCAN, OFF);
  scanC_kernel<<<NB_SCAN, 256, 0, stream>>>(DEG, BSUM, OFF, CUR, N_NODES);
  fill_kernel<<<1024, 256, 0, stream>>>(edge_src + N_EDGES, edge_dst + N_EDGES,
                                        edge_type + N_EDGES, CUR, EPK, N_EDGES);
  gather_mean_kernel<<<GATHER_BLOCKS, 256, 0, stream>>>(OFF, EPK, H, REL, MEANB, 1,
                                                        ACC, nullptr, N_NODES);

  final_kernel<<<2048, 256, 0, stream>>>(MEANB, ACC, bn_gamma, bn_beta,
                                         fc0_w, fc0_b, fc1_w, fc1_b,
                                         fc2_w, fc2_b, out, N_NODES);
}